// Round 3
// 853.313 us; speedup vs baseline: 1.2042x; 1.2042x over previous
//
#include <hip/hip_runtime.h>
#include <math.h>

#define B_ 4
#define N_ 1024
#define H_ 1024
#define NH_ 16
#define D_ 64

#define SZ_ATTN (B_*NH_*N_)
#define SZ_HEADS (B_*NH_*N_*D_)

// ---------------------------------------------------------------------------
// padd[b] = index of first zero in padding_vector[b,:], or N
// ---------------------------------------------------------------------------
__global__ void padd_kernel(const int* __restrict__ pv, int* __restrict__ padd) {
    __shared__ int mn;
    const int b = blockIdx.x;
    if (threadIdx.x == 0) mn = N_;
    __syncthreads();
    for (int m = threadIdx.x; m < N_; m += blockDim.x)
        if (pv[b*N_ + m] == 0) atomicMin(&mn, m);
    __syncthreads();
    if (threadIdx.x == 0) padd[b] = mn;
}

// ---------------------------------------------------------------------------
// Q/K/V projections in one launch (blockIdx.z selects weight/out).
// 128x128 tile, 256 threads, 8x8 outputs per thread as 2x2 blocks of 4x4.
// C[i][j] = sum_k X[i,k]*W[j,k] + bias[j], written in heads layout.
// ---------------------------------------------------------------------------
__global__ __launch_bounds__(256)
void proj3_kernel(const float* __restrict__ X,
                  const float* __restrict__ Wq, const float* __restrict__ bq_, float* __restrict__ Oq,
                  const float* __restrict__ Wk, const float* __restrict__ bk_, float* __restrict__ Ok,
                  const float* __restrict__ Wv, const float* __restrict__ bv_, float* __restrict__ Ov)
{
    const int which = blockIdx.z;
    const float* __restrict__ W    = (which == 0) ? Wq  : (which == 1) ? Wk  : Wv;
    const float* __restrict__ bias = (which == 0) ? bq_ : (which == 1) ? bk_ : bv_;
    float* __restrict__ outH       = (which == 0) ? Oq  : (which == 1) ? Ok  : Ov;

    __shared__ float As[16*132];   // k-major: As[k*132 + row]
    __shared__ float Bs[16*132];
    const int tid = threadIdx.x;
    const int tx = tid & 15, ty = tid >> 4;
    const int i0 = blockIdx.y * 128;
    const int j0 = blockIdx.x * 128;

    float acc[2][2][4][4];
    #pragma unroll
    for (int rh = 0; rh < 2; ++rh)
        #pragma unroll
        for (int ch = 0; ch < 2; ++ch)
            #pragma unroll
            for (int r = 0; r < 4; ++r)
                #pragma unroll
                for (int c = 0; c < 4; ++c) acc[rh][ch][r][c] = 0.f;

    for (int kt = 0; kt < H_; kt += 16) {
        __syncthreads();
        #pragma unroll
        for (int l = 0; l < 2; ++l) {
            const int idx = tid + 256*l;          // 0..511
            const int row = idx >> 2, c4 = idx & 3;
            const float4 xv = *(const float4*)(X + (size_t)(i0+row)*H_ + kt + c4*4);
            As[(c4*4+0)*132 + row] = xv.x; As[(c4*4+1)*132 + row] = xv.y;
            As[(c4*4+2)*132 + row] = xv.z; As[(c4*4+3)*132 + row] = xv.w;
            const float4 wv = *(const float4*)(W + (size_t)(j0+row)*H_ + kt + c4*4);
            Bs[(c4*4+0)*132 + row] = wv.x; Bs[(c4*4+1)*132 + row] = wv.y;
            Bs[(c4*4+2)*132 + row] = wv.z; Bs[(c4*4+3)*132 + row] = wv.w;
        }
        __syncthreads();
        #pragma unroll
        for (int kk = 0; kk < 16; ++kk) {
            const float4 a0 = *(const float4*)&As[kk*132 + ty*4];
            const float4 a1 = *(const float4*)&As[kk*132 + 64 + ty*4];
            const float4 b0 = *(const float4*)&Bs[kk*132 + tx*4];
            const float4 b1 = *(const float4*)&Bs[kk*132 + 64 + tx*4];
            const float ar[2][4] = {{a0.x,a0.y,a0.z,a0.w},{a1.x,a1.y,a1.z,a1.w}};
            const float br[2][4] = {{b0.x,b0.y,b0.z,b0.w},{b1.x,b1.y,b1.z,b1.w}};
            #pragma unroll
            for (int rh = 0; rh < 2; ++rh)
                #pragma unroll
                for (int r = 0; r < 4; ++r)
                    #pragma unroll
                    for (int ch = 0; ch < 2; ++ch)
                        #pragma unroll
                        for (int c = 0; c < 4; ++c)
                            acc[rh][ch][r][c] += ar[rh][r]*br[ch][c];
        }
    }

    #pragma unroll
    for (int rh = 0; rh < 2; ++rh)
        #pragma unroll
        for (int r = 0; r < 4; ++r) {
            const int i = i0 + rh*64 + ty*4 + r;
            const int bb = i >> 10, n = i & 1023;
            #pragma unroll
            for (int ch = 0; ch < 2; ++ch) {
                const int j = j0 + ch*64 + tx*4;   // 4 cols within one head
                const int head = j >> 6;
                const float4 b4 = *(const float4*)(bias + j);
                float4 o;
                o.x = acc[rh][ch][r][0] + b4.x;
                o.y = acc[rh][ch][r][1] + b4.y;
                o.z = acc[rh][ch][r][2] + b4.z;
                o.w = acc[rh][ch][r][3] + b4.w;
                *(float4*)(outH + ((size_t)(bb*NH_ + head)*N_ + n)*D_ + (j & 63)) = o;
            }
        }
}

// ---------------------------------------------------------------------------
// Fused attention, 128-row n-tile per block (256 threads, 2 blocks/CU).
// Pass 1: 128-wide m-steps, 8x8 acc per thread: QK^T -> write raw scaled S ->
//         online masked row max/sumexp (shuffle over the 16 tx-lanes).
// Pass 2: 64-wide m-steps: stage P^T[m][n] (stride 132) + V[m][d] (stride 68),
//         colsums -> attn atomics, P@V (2x4x4 acc, all-b128 reads) -> ctx.
// ---------------------------------------------------------------------------
__global__ __launch_bounds__(256)
void fused_attn_kernel(const float* __restrict__ Q, const float* __restrict__ K,
                       const float* __restrict__ Vh, const int* __restrict__ padd,
                       float* __restrict__ S, float* __restrict__ ctx,
                       float* __restrict__ attn)
{
    __shared__ float ldsA[64*132];   // pass1: Q^T[k][n]   pass2: P^T[m][n]
    __shared__ float ldsB[64*132];   // pass1: K^T[k][m]   pass2: V[m][d] (stride 68)
    __shared__ float smx[128], sinv[128];
    __shared__ float cred[256];

    const int tid = threadIdx.x;
    const int tx = tid & 15, ty = tid >> 4;
    const int bh = blockIdx.y;
    const int n0 = blockIdx.x * 128;
    const int b  = bh >> 4;
    const int pd = padd[b];
    const float* Qb = Q  + (size_t)bh*N_*D_;
    const float* Kb = K  + (size_t)bh*N_*D_;
    const float* Vb = Vh + (size_t)bh*N_*D_;
    float* Sb = S + (size_t)bh*N_*N_;

    // stage Q^T (k-major, 128 rows)
    #pragma unroll
    for (int l = 0; l < 8; ++l) {
        const int idx = tid + 256*l;          // 0..2047
        const int row = idx >> 4, c4 = idx & 15;
        const float4 q4 = *(const float4*)(Qb + (size_t)(n0+row)*D_ + c4*4);
        ldsA[(c4*4+0)*132 + row] = q4.x; ldsA[(c4*4+1)*132 + row] = q4.y;
        ldsA[(c4*4+2)*132 + row] = q4.z; ldsA[(c4*4+3)*132 + row] = q4.w;
    }

    float run_mx[2][4], run_sm[2][4];
    #pragma unroll
    for (int rh = 0; rh < 2; ++rh)
        #pragma unroll
        for (int r = 0; r < 4; ++r) { run_mx[rh][r] = -INFINITY; run_sm[rh][r] = 0.f; }

    // ---------------- pass 1: scores + online stats ----------------
    for (int m0 = 0; m0 < N_; m0 += 128) {
        #pragma unroll
        for (int l = 0; l < 8; ++l) {
            const int idx = tid + 256*l;
            const int row = idx >> 4, c4 = idx & 15;
            const float4 k4 = *(const float4*)(Kb + (size_t)(m0+row)*D_ + c4*4);
            ldsB[(c4*4+0)*132 + row] = k4.x; ldsB[(c4*4+1)*132 + row] = k4.y;
            ldsB[(c4*4+2)*132 + row] = k4.z; ldsB[(c4*4+3)*132 + row] = k4.w;
        }
        __syncthreads();

        float sacc[2][2][4][4];
        #pragma unroll
        for (int rh = 0; rh < 2; ++rh)
            #pragma unroll
            for (int ch = 0; ch < 2; ++ch)
                #pragma unroll
                for (int r = 0; r < 4; ++r)
                    #pragma unroll
                    for (int c = 0; c < 4; ++c) sacc[rh][ch][r][c] = 0.f;

        #pragma unroll 4
        for (int kk = 0; kk < 64; ++kk) {
            const float4 a0 = *(const float4*)&ldsA[kk*132 + ty*4];
            const float4 a1 = *(const float4*)&ldsA[kk*132 + 64 + ty*4];
            const float4 b0 = *(const float4*)&ldsB[kk*132 + tx*4];
            const float4 b1 = *(const float4*)&ldsB[kk*132 + 64 + tx*4];
            const float ar[2][4] = {{a0.x,a0.y,a0.z,a0.w},{a1.x,a1.y,a1.z,a1.w}};
            const float br[2][4] = {{b0.x,b0.y,b0.z,b0.w},{b1.x,b1.y,b1.z,b1.w}};
            #pragma unroll
            for (int rh = 0; rh < 2; ++rh)
                #pragma unroll
                for (int r = 0; r < 4; ++r)
                    #pragma unroll
                    for (int ch = 0; ch < 2; ++ch)
                        #pragma unroll
                        for (int c = 0; c < 4; ++c)
                            sacc[rh][ch][r][c] += ar[rh][r]*br[ch][c];
        }

        // scale + write raw scores (all rows/cols, unmasked)
        #pragma unroll
        for (int rh = 0; rh < 2; ++rh)
            #pragma unroll
            for (int r = 0; r < 4; ++r) {
                const int n = n0 + rh*64 + ty*4 + r;
                #pragma unroll
                for (int ch = 0; ch < 2; ++ch) {
                    #pragma unroll
                    for (int c = 0; c < 4; ++c) sacc[rh][ch][r][c] *= 0.125f;
                    float4 o;
                    o.x = sacc[rh][ch][r][0]; o.y = sacc[rh][ch][r][1];
                    o.z = sacc[rh][ch][r][2]; o.w = sacc[rh][ch][r][3];
                    *(float4*)(Sb + (size_t)n*N_ + m0 + ch*64 + tx*4) = o;
                }
            }

        // online masked max / sum-exp per row
        if (m0 < pd) {
            #pragma unroll
            for (int rh = 0; rh < 2; ++rh)
                #pragma unroll
                for (int r = 0; r < 4; ++r) {
                    float tm = -INFINITY;
                    #pragma unroll
                    for (int ch = 0; ch < 2; ++ch)
                        #pragma unroll
                        for (int c = 0; c < 4; ++c)
                            if (m0 + ch*64 + tx*4 + c < pd)
                                tm = fmaxf(tm, sacc[rh][ch][r][c]);
                    tm = fmaxf(tm, __shfl_xor(tm, 1, 64));
                    tm = fmaxf(tm, __shfl_xor(tm, 2, 64));
                    tm = fmaxf(tm, __shfl_xor(tm, 4, 64));
                    tm = fmaxf(tm, __shfl_xor(tm, 8, 64));
                    if (n0 + rh*64 + ty*4 + r < pd) {
                        const float nm = fmaxf(run_mx[rh][r], tm);
                        float s = 0.f;
                        #pragma unroll
                        for (int ch = 0; ch < 2; ++ch)
                            #pragma unroll
                            for (int c = 0; c < 4; ++c)
                                if (m0 + ch*64 + tx*4 + c < pd)
                                    s += __expf(sacc[rh][ch][r][c] - nm);
                        run_sm[rh][r] = run_sm[rh][r]*__expf(run_mx[rh][r] - nm) + s;
                        run_mx[rh][r] = nm;
                    }
                }
        }
        __syncthreads();   // protect ldsB before next tile's staging
    }

    // fully-masked n-tile: scores already written; ctx rows are zero
    if (n0 >= pd) {
        #pragma unroll
        for (int rh = 0; rh < 2; ++rh)
            #pragma unroll
            for (int r = 0; r < 4; ++r) {
                float4 z; z.x = z.y = z.z = z.w = 0.f;
                *(float4*)(ctx + ((size_t)bh*N_ + n0 + rh*64 + ty*4 + r)*D_ + tx*4) = z;
            }
        return;
    }

    // finalize per-row stats into LDS
    #pragma unroll
    for (int rh = 0; rh < 2; ++rh)
        #pragma unroll
        for (int r = 0; r < 4; ++r) {
            float s = run_sm[rh][r];
            s += __shfl_xor(s, 1, 64);
            s += __shfl_xor(s, 2, 64);
            s += __shfl_xor(s, 4, 64);
            s += __shfl_xor(s, 8, 64);
            if (tx == 0) {
                const int rowt = rh*64 + ty*4 + r;
                const bool v = (n0 + rowt) < pd;
                smx[rowt]  = v ? run_mx[rh][r] : 0.f;
                sinv[rowt] = v ? 1.f/s        : 0.f;
            }
        }
    __syncthreads();

    // ---------------- pass 2: probs -> attn colsums + P@V ----------------
    float cacc[2][4][4];
    #pragma unroll
    for (int rh = 0; rh < 2; ++rh)
        #pragma unroll
        for (int r = 0; r < 4; ++r)
            #pragma unroll
            for (int c = 0; c < 4; ++c) cacc[rh][r][c] = 0.f;

    for (int m0 = 0; m0 < pd; m0 += 64) {
        // stage P^T[m][n] (stride 132)
        #pragma unroll
        for (int l = 0; l < 8; ++l) {
            const int idx = tid + 256*l;      // 0..2047
            const int nrow = idx >> 4, c4 = idx & 15;
            const int n = n0 + nrow;
            const int m = m0 + c4*4;
            const float4 s4 = *(const float4*)(Sb + (size_t)n*N_ + m);
            const bool rv = n < pd;
            const float fmx = smx[nrow], fiv = sinv[nrow];
            ldsA[(c4*4+0)*132 + nrow] = (rv && m+0 < pd) ? __expf(s4.x - fmx)*fiv : 0.f;
            ldsA[(c4*4+1)*132 + nrow] = (rv && m+1 < pd) ? __expf(s4.y - fmx)*fiv : 0.f;
            ldsA[(c4*4+2)*132 + nrow] = (rv && m+2 < pd) ? __expf(s4.z - fmx)*fiv : 0.f;
            ldsA[(c4*4+3)*132 + nrow] = (rv && m+3 < pd) ? __expf(s4.w - fmx)*fiv : 0.f;
        }
        // stage V[m][d] (stride 68, vector stores)
        #pragma unroll
        for (int l = 0; l < 4; ++l) {
            const int idx = tid + 256*l;      // 0..1023
            const int vrow = idx >> 4, c4 = idx & 15;
            *(float4*)&ldsB[vrow*68 + c4*4] =
                *(const float4*)(Vb + (size_t)(m0+vrow)*D_ + c4*4);
        }
        __syncthreads();

        // column sums of this probs tile -> attention_values
        {
            const int ml = tid & 63, q = tid >> 6;
            float cs = 0.f;
            #pragma unroll
            for (int i = 0; i < 32; ++i)
                cs += ldsA[ml*132 + ((q*32 + i + ml) & 127)];   // rotated reads
            cred[tid] = cs;
        }
        __syncthreads();
        if (tid < 64) {
            const float vtot = cred[tid] + cred[tid+64] + cred[tid+128] + cred[tid+192];
            atomicAdd(&attn[(size_t)bh*N_ + m0 + tid], vtot);
        }

        // tile GEMM: ctx[n][d] += sum_m P^T[m][n] * V[m][d]
        #pragma unroll 8
        for (int m = 0; m < 64; ++m) {
            const float4 a0 = *(const float4*)&ldsA[m*132 + ty*4];
            const float4 a1 = *(const float4*)&ldsA[m*132 + 64 + ty*4];
            const float4 b4 = *(const float4*)&ldsB[m*68 + tx*4];
            const float ar[2][4] = {{a0.x,a0.y,a0.z,a0.w},{a1.x,a1.y,a1.z,a1.w}};
            const float br[4] = {b4.x, b4.y, b4.z, b4.w};
            #pragma unroll
            for (int rh = 0; rh < 2; ++rh)
                #pragma unroll
                for (int r = 0; r < 4; ++r)
                    #pragma unroll
                    for (int c = 0; c < 4; ++c)
                        cacc[rh][r][c] += ar[rh][r]*br[c];
        }
        __syncthreads();   // protect LDS before next tile's staging
    }

    #pragma unroll
    for (int rh = 0; rh < 2; ++rh)
        #pragma unroll
        for (int r = 0; r < 4; ++r) {
            const int n = n0 + rh*64 + ty*4 + r;
            float4 o;
            o.x = cacc[rh][r][0]; o.y = cacc[rh][r][1];
            o.z = cacc[rh][r][2]; o.w = cacc[rh][r][3];
            *(float4*)(ctx + ((size_t)bh*N_ + n)*D_ + tx*4) = o;
        }
}

// ---------------------------------------------------------------------------
extern "C" void kernel_launch(void* const* d_in, const int* in_sizes, int n_in,
                              void* d_out, int out_size, void* d_ws, size_t ws_size,
                              hipStream_t stream)
{
    const float* hs = (const float*)d_in[0];
    const int*   pv = (const int*)d_in[1];
    const float* Wq = (const float*)d_in[2];
    const float* bq = (const float*)d_in[3];
    const float* Wk = (const float*)d_in[4];
    const float* bk = (const float*)d_in[5];
    const float* Wv = (const float*)d_in[6];
    const float* bv = (const float*)d_in[7];
    float* out = (float*)d_out;

    float* out_attn = out;                       // (B,NH,N)
    float* out_k    = out_attn + SZ_ATTN;        // (B,NH,N,D)
    float* out_q    = out_k + SZ_HEADS;          // (B,NH,N,D)
    float* out_ctx  = out_q + SZ_HEADS;          // (B,NH,N,D)
    float* out_sc   = out_ctx + SZ_HEADS;        // (B,NH,N,N)

    int*   padd = (int*)d_ws;
    float* v_ws = (float*)((char*)d_ws + 256);   // (B,NH,N,D) 16 MB

    hipMemsetAsync(out_attn, 0, SZ_ATTN*sizeof(float), stream);
    padd_kernel<<<B_, 256, 0, stream>>>(pv, padd);

    dim3 pg(H_/128, (B_*N_)/128, 3);             // (8, 32, 3)
    proj3_kernel<<<pg, 256, 0, stream>>>(hs, Wq, bq, out_q,
                                         Wk, bk, out_k,
                                         Wv, bv, v_ws);

    dim3 fg(N_/128, B_*NH_);                     // (8, 64)
    fused_attn_kernel<<<fg, 256, 0, stream>>>(out_q, out_k, v_ws, padd,
                                              out_sc, out_ctx, out_attn);
}

// Round 4
// 667.136 us; speedup vs baseline: 1.5403x; 1.2791x over previous
//
#include <hip/hip_runtime.h>
#include <math.h>

#define B_ 4
#define N_ 1024
#define H_ 1024
#define NH_ 16
#define D_ 64

#define SZ_ATTN (B_*NH_*N_)
#define SZ_HEADS (B_*NH_*N_*D_)

typedef __attribute__((ext_vector_type(8))) short short8v;
typedef __attribute__((ext_vector_type(4))) float floatx4;

__device__ inline unsigned short f2bf(float x) {
    union { float f; unsigned int u; } v; v.f = x;
    unsigned int r = v.u + 0x7FFFu + ((v.u >> 16) & 1u);   // RNE
    return (unsigned short)(r >> 16);
}

// ---------------------------------------------------------------------------
// padd[b] = index of first zero in padding_vector[b,:], or N
// ---------------------------------------------------------------------------
__global__ void padd_kernel(const int* __restrict__ pv, int* __restrict__ padd) {
    __shared__ int mn;
    const int b = blockIdx.x;
    if (threadIdx.x == 0) mn = N_;
    __syncthreads();
    for (int m = threadIdx.x; m < N_; m += blockDim.x)
        if (pv[b*N_ + m] == 0) atomicMin(&mn, m);
    __syncthreads();
    if (threadIdx.x == 0) padd[b] = mn;
}

// ---------------------------------------------------------------------------
// Q/K/V projections via bf16 MFMA (blockIdx.z selects weight/out).
// 128x128 tile, BK=64, 4 waves (2x2), each wave 64x64 = 4x4 frags of 16x16.
// fp32 global -> bf16 RNE -> XOR-swizzled LDS -> mfma_f32_16x16x32_bf16.
// C[i][j] = sum_k X[i,k]*W[j,k] + bias[j], fp32 accumulate, heads layout out.
// ---------------------------------------------------------------------------
__global__ __launch_bounds__(256)
void proj3_mfma_kernel(const float* __restrict__ X,
                       const float* __restrict__ Wq, const float* __restrict__ bq_, float* __restrict__ Oq,
                       const float* __restrict__ Wk, const float* __restrict__ bk_, float* __restrict__ Ok,
                       const float* __restrict__ Wv, const float* __restrict__ bv_, float* __restrict__ Ov)
{
    const int which = blockIdx.z;
    const float* __restrict__ W    = (which == 0) ? Wq  : (which == 1) ? Wk  : Wv;
    const float* __restrict__ bias = (which == 0) ? bq_ : (which == 1) ? bk_ : bv_;
    float* __restrict__ outH       = (which == 0) ? Oq  : (which == 1) ? Ok  : Ov;

    // bf16 tiles, 128 rows x 64 k, 16B chunks XOR-swizzled by (row&7)
    __shared__ __align__(16) unsigned short Abf[128*64];
    __shared__ __align__(16) unsigned short Bbf[128*64];

    const int tid  = threadIdx.x;
    const int lane = tid & 63;
    const int w    = tid >> 6;
    const int wr   = w >> 1, wc = w & 1;       // wave grid 2x2
    const int fr   = lane & 15, hi = lane >> 4;
    const int i0 = blockIdx.y * 128;
    const int j0 = blockIdx.x * 128;

    floatx4 acc[4][4];
    #pragma unroll
    for (int mi = 0; mi < 4; ++mi)
        #pragma unroll
        for (int ni = 0; ni < 4; ++ni)
            acc[mi][ni] = (floatx4){0.f, 0.f, 0.f, 0.f};

    for (int kt = 0; kt < H_; kt += 64) {
        __syncthreads();
        // stage X and W tiles: 8192 bf16 each; 4 chunks of 8 per thread
        #pragma unroll
        for (int l = 0; l < 4; ++l) {
            const int e = tid + 256*l;             // 0..1023
            const int row = e >> 3, kc = e & 7;    // row 0..127, 8-elem chunk
            const int sw = ((kc ^ (row & 7)) << 3);
            {
                const float* src = X + (size_t)(i0+row)*H_ + kt + kc*8;
                const float4 xa = *(const float4*)(src);
                const float4 xb = *(const float4*)(src + 4);
                short8v pk;
                pk[0] = (short)f2bf(xa.x); pk[1] = (short)f2bf(xa.y);
                pk[2] = (short)f2bf(xa.z); pk[3] = (short)f2bf(xa.w);
                pk[4] = (short)f2bf(xb.x); pk[5] = (short)f2bf(xb.y);
                pk[6] = (short)f2bf(xb.z); pk[7] = (short)f2bf(xb.w);
                *(short8v*)&Abf[row*64 + sw] = pk;
            }
            {
                const float* src = W + (size_t)(j0+row)*H_ + kt + kc*8;
                const float4 wa = *(const float4*)(src);
                const float4 wb = *(const float4*)(src + 4);
                short8v pk;
                pk[0] = (short)f2bf(wa.x); pk[1] = (short)f2bf(wa.y);
                pk[2] = (short)f2bf(wa.z); pk[3] = (short)f2bf(wa.w);
                pk[4] = (short)f2bf(wb.x); pk[5] = (short)f2bf(wb.y);
                pk[6] = (short)f2bf(wb.z); pk[7] = (short)f2bf(wb.w);
                *(short8v*)&Bbf[row*64 + sw] = pk;
            }
        }
        __syncthreads();

        #pragma unroll
        for (int ks = 0; ks < 2; ++ks) {
            short8v a[4], b[4];
            #pragma unroll
            for (int mi = 0; mi < 4; ++mi) {
                const int row = wr*64 + mi*16 + fr;
                a[mi] = *(const short8v*)&Abf[row*64 + (((ks*4 + hi) ^ (fr & 7)) << 3)];
            }
            #pragma unroll
            for (int ni = 0; ni < 4; ++ni) {
                const int row = wc*64 + ni*16 + fr;
                b[ni] = *(const short8v*)&Bbf[row*64 + (((ks*4 + hi) ^ (fr & 7)) << 3)];
            }
            #pragma unroll
            for (int mi = 0; mi < 4; ++mi)
                #pragma unroll
                for (int ni = 0; ni < 4; ++ni)
                    acc[mi][ni] = __builtin_amdgcn_mfma_f32_16x16x32_bf16(
                        a[mi], b[ni], acc[mi][ni], 0, 0, 0);
        }
    }

    // epilogue: C/D layout col = lane&15, row = (lane>>4)*4 + reg
    #pragma unroll
    for (int ni = 0; ni < 4; ++ni) {
        const int j = j0 + wc*64 + ni*16 + fr;
        const int head = j >> 6, d = j & 63;
        const float bvj = bias[j];
        #pragma unroll
        for (int mi = 0; mi < 4; ++mi) {
            #pragma unroll
            for (int reg = 0; reg < 4; ++reg) {
                const int i = i0 + wr*64 + mi*16 + hi*4 + reg;
                const int bb = i >> 10, n = i & 1023;
                outH[((size_t)(bb*NH_ + head)*N_ + n)*D_ + d] = acc[mi][ni][reg] + bvj;
            }
        }
    }
}

// ---------------------------------------------------------------------------
// Fused attention, 128-row n-tile per block (256 threads).
// Pass 1: 128-wide m-steps, 8x8 acc: QK^T -> raw scaled S -> online stats.
// Pass 2: 64-wide m-steps: P^T[m][n] (stride 132) + V[m][d] (stride 68),
//         colsums -> attn atomics, P@V (2x4x4 acc, all-b128 reads) -> ctx.
// ---------------------------------------------------------------------------
__global__ __launch_bounds__(256)
void fused_attn_kernel(const float* __restrict__ Q, const float* __restrict__ K,
                       const float* __restrict__ Vh, const int* __restrict__ padd,
                       float* __restrict__ S, float* __restrict__ ctx,
                       float* __restrict__ attn)
{
    __shared__ float ldsA[64*132];   // pass1: Q^T[k][n]   pass2: P^T[m][n]
    __shared__ float ldsB[64*132];   // pass1: K^T[k][m]   pass2: V[m][d] (stride 68)
    __shared__ float smx[128], sinv[128];
    __shared__ float cred[256];

    const int tid = threadIdx.x;
    const int tx = tid & 15, ty = tid >> 4;
    const int bh = blockIdx.y;
    const int n0 = blockIdx.x * 128;
    const int b  = bh >> 4;
    const int pd = padd[b];
    const float* Qb = Q  + (size_t)bh*N_*D_;
    const float* Kb = K  + (size_t)bh*N_*D_;
    const float* Vb = Vh + (size_t)bh*N_*D_;
    float* Sb = S + (size_t)bh*N_*N_;

    // stage Q^T (k-major, 128 rows)
    #pragma unroll
    for (int l = 0; l < 8; ++l) {
        const int idx = tid + 256*l;          // 0..2047
        const int row = idx >> 4, c4 = idx & 15;
        const float4 q4 = *(const float4*)(Qb + (size_t)(n0+row)*D_ + c4*4);
        ldsA[(c4*4+0)*132 + row] = q4.x; ldsA[(c4*4+1)*132 + row] = q4.y;
        ldsA[(c4*4+2)*132 + row] = q4.z; ldsA[(c4*4+3)*132 + row] = q4.w;
    }

    float run_mx[2][4], run_sm[2][4];
    #pragma unroll
    for (int rh = 0; rh < 2; ++rh)
        #pragma unroll
        for (int r = 0; r < 4; ++r) { run_mx[rh][r] = -INFINITY; run_sm[rh][r] = 0.f; }

    // ---------------- pass 1: scores + online stats ----------------
    for (int m0 = 0; m0 < N_; m0 += 128) {
        #pragma unroll
        for (int l = 0; l < 8; ++l) {
            const int idx = tid + 256*l;
            const int row = idx >> 4, c4 = idx & 15;
            const float4 k4 = *(const float4*)(Kb + (size_t)(m0+row)*D_ + c4*4);
            ldsB[(c4*4+0)*132 + row] = k4.x; ldsB[(c4*4+1)*132 + row] = k4.y;
            ldsB[(c4*4+2)*132 + row] = k4.z; ldsB[(c4*4+3)*132 + row] = k4.w;
        }
        __syncthreads();

        float sacc[2][2][4][4];
        #pragma unroll
        for (int rh = 0; rh < 2; ++rh)
            #pragma unroll
            for (int ch = 0; ch < 2; ++ch)
                #pragma unroll
                for (int r = 0; r < 4; ++r)
                    #pragma unroll
                    for (int c = 0; c < 4; ++c) sacc[rh][ch][r][c] = 0.f;

        #pragma unroll 4
        for (int kk = 0; kk < 64; ++kk) {
            const float4 a0 = *(const float4*)&ldsA[kk*132 + ty*4];
            const float4 a1 = *(const float4*)&ldsA[kk*132 + 64 + ty*4];
            const float4 b0 = *(const float4*)&ldsB[kk*132 + tx*4];
            const float4 b1 = *(const float4*)&ldsB[kk*132 + 64 + tx*4];
            const float ar[2][4] = {{a0.x,a0.y,a0.z,a0.w},{a1.x,a1.y,a1.z,a1.w}};
            const float br[2][4] = {{b0.x,b0.y,b0.z,b0.w},{b1.x,b1.y,b1.z,b1.w}};
            #pragma unroll
            for (int rh = 0; rh < 2; ++rh)
                #pragma unroll
                for (int r = 0; r < 4; ++r)
                    #pragma unroll
                    for (int ch = 0; ch < 2; ++ch)
                        #pragma unroll
                        for (int c = 0; c < 4; ++c)
                            sacc[rh][ch][r][c] += ar[rh][r]*br[ch][c];
        }

        // scale + write raw scores (all rows/cols, unmasked)
        #pragma unroll
        for (int rh = 0; rh < 2; ++rh)
            #pragma unroll
            for (int r = 0; r < 4; ++r) {
                const int n = n0 + rh*64 + ty*4 + r;
                #pragma unroll
                for (int ch = 0; ch < 2; ++ch) {
                    #pragma unroll
                    for (int c = 0; c < 4; ++c) sacc[rh][ch][r][c] *= 0.125f;
                    float4 o;
                    o.x = sacc[rh][ch][r][0]; o.y = sacc[rh][ch][r][1];
                    o.z = sacc[rh][ch][r][2]; o.w = sacc[rh][ch][r][3];
                    *(float4*)(Sb + (size_t)n*N_ + m0 + ch*64 + tx*4) = o;
                }
            }

        // online masked max / sum-exp per row
        if (m0 < pd) {
            #pragma unroll
            for (int rh = 0; rh < 2; ++rh)
                #pragma unroll
                for (int r = 0; r < 4; ++r) {
                    float tm = -INFINITY;
                    #pragma unroll
                    for (int ch = 0; ch < 2; ++ch)
                        #pragma unroll
                        for (int c = 0; c < 4; ++c)
                            if (m0 + ch*64 + tx*4 + c < pd)
                                tm = fmaxf(tm, sacc[rh][ch][r][c]);
                    tm = fmaxf(tm, __shfl_xor(tm, 1, 64));
                    tm = fmaxf(tm, __shfl_xor(tm, 2, 64));
                    tm = fmaxf(tm, __shfl_xor(tm, 4, 64));
                    tm = fmaxf(tm, __shfl_xor(tm, 8, 64));
                    if (n0 + rh*64 + ty*4 + r < pd) {
                        const float nm = fmaxf(run_mx[rh][r], tm);
                        float s = 0.f;
                        #pragma unroll
                        for (int ch = 0; ch < 2; ++ch)
                            #pragma unroll
                            for (int c = 0; c < 4; ++c)
                                if (m0 + ch*64 + tx*4 + c < pd)
                                    s += __expf(sacc[rh][ch][r][c] - nm);
                        run_sm[rh][r] = run_sm[rh][r]*__expf(run_mx[rh][r] - nm) + s;
                        run_mx[rh][r] = nm;
                    }
                }
        }
        __syncthreads();   // protect ldsB before next tile's staging
    }

    // fully-masked n-tile: scores already written; ctx rows are zero
    if (n0 >= pd) {
        #pragma unroll
        for (int rh = 0; rh < 2; ++rh)
            #pragma unroll
            for (int r = 0; r < 4; ++r) {
                float4 z; z.x = z.y = z.z = z.w = 0.f;
                *(float4*)(ctx + ((size_t)bh*N_ + n0 + rh*64 + ty*4 + r)*D_ + tx*4) = z;
            }
        return;
    }

    // finalize per-row stats into LDS
    #pragma unroll
    for (int rh = 0; rh < 2; ++rh)
        #pragma unroll
        for (int r = 0; r < 4; ++r) {
            float s = run_sm[rh][r];
            s += __shfl_xor(s, 1, 64);
            s += __shfl_xor(s, 2, 64);
            s += __shfl_xor(s, 4, 64);
            s += __shfl_xor(s, 8, 64);
            if (tx == 0) {
                const int rowt = rh*64 + ty*4 + r;
                const bool v = (n0 + rowt) < pd;
                smx[rowt]  = v ? run_mx[rh][r] : 0.f;
                sinv[rowt] = v ? 1.f/s        : 0.f;
            }
        }
    __syncthreads();

    // ---------------- pass 2: probs -> attn colsums + P@V ----------------
    float cacc[2][4][4];
    #pragma unroll
    for (int rh = 0; rh < 2; ++rh)
        #pragma unroll
        for (int r = 0; r < 4; ++r)
            #pragma unroll
            for (int c = 0; c < 4; ++c) cacc[rh][r][c] = 0.f;

    for (int m0 = 0; m0 < pd; m0 += 64) {
        // stage P^T[m][n] (stride 132)
        #pragma unroll
        for (int l = 0; l < 8; ++l) {
            const int idx = tid + 256*l;      // 0..2047
            const int nrow = idx >> 4, c4 = idx & 15;
            const int n = n0 + nrow;
            const int m = m0 + c4*4;
            const float4 s4 = *(const float4*)(Sb + (size_t)n*N_ + m);
            const bool rv = n < pd;
            const float fmx = smx[nrow], fiv = sinv[nrow];
            ldsA[(c4*4+0)*132 + nrow] = (rv && m+0 < pd) ? __expf(s4.x - fmx)*fiv : 0.f;
            ldsA[(c4*4+1)*132 + nrow] = (rv && m+1 < pd) ? __expf(s4.y - fmx)*fiv : 0.f;
            ldsA[(c4*4+2)*132 + nrow] = (rv && m+2 < pd) ? __expf(s4.z - fmx)*fiv : 0.f;
            ldsA[(c4*4+3)*132 + nrow] = (rv && m+3 < pd) ? __expf(s4.w - fmx)*fiv : 0.f;
        }
        // stage V[m][d] (stride 68, vector stores)
        #pragma unroll
        for (int l = 0; l < 4; ++l) {
            const int idx = tid + 256*l;      // 0..1023
            const int vrow = idx >> 4, c4 = idx & 15;
            *(float4*)&ldsB[vrow*68 + c4*4] =
                *(const float4*)(Vb + (size_t)(m0+vrow)*D_ + c4*4);
        }
        __syncthreads();

        // column sums of this probs tile -> attention_values
        {
            const int ml = tid & 63, q = tid >> 6;
            float cs = 0.f;
            #pragma unroll
            for (int i = 0; i < 32; ++i)
                cs += ldsA[ml*132 + ((q*32 + i + ml) & 127)];   // rotated reads
            cred[tid] = cs;
        }
        __syncthreads();
        if (tid < 64) {
            const float vtot = cred[tid] + cred[tid+64] + cred[tid+128] + cred[tid+192];
            atomicAdd(&attn[(size_t)bh*N_ + m0 + tid], vtot);
        }

        // tile GEMM: ctx[n][d] += sum_m P^T[m][n] * V[m][d]
        #pragma unroll 8
        for (int m = 0; m < 64; ++m) {
            const float4 a0 = *(const float4*)&ldsA[m*132 + ty*4];
            const float4 a1 = *(const float4*)&ldsA[m*132 + 64 + ty*4];
            const float4 b4 = *(const float4*)&ldsB[m*68 + tx*4];
            const float ar[2][4] = {{a0.x,a0.y,a0.z,a0.w},{a1.x,a1.y,a1.z,a1.w}};
            const float br[4] = {b4.x, b4.y, b4.z, b4.w};
            #pragma unroll
            for (int rh = 0; rh < 2; ++rh)
                #pragma unroll
                for (int r = 0; r < 4; ++r)
                    #pragma unroll
                    for (int c = 0; c < 4; ++c)
                        cacc[rh][r][c] += ar[rh][r]*br[c];
        }
        __syncthreads();   // protect LDS before next tile's staging
    }

    #pragma unroll
    for (int rh = 0; rh < 2; ++rh)
        #pragma unroll
        for (int r = 0; r < 4; ++r) {
            const int n = n0 + rh*64 + ty*4 + r;
            float4 o;
            o.x = cacc[rh][r][0]; o.y = cacc[rh][r][1];
            o.z = cacc[rh][r][2]; o.w = cacc[rh][r][3];
            *(float4*)(ctx + ((size_t)bh*N_ + n)*D_ + tx*4) = o;
        }
}

// ---------------------------------------------------------------------------
extern "C" void kernel_launch(void* const* d_in, const int* in_sizes, int n_in,
                              void* d_out, int out_size, void* d_ws, size_t ws_size,
                              hipStream_t stream)
{
    const float* hs = (const float*)d_in[0];
    const int*   pv = (const int*)d_in[1];
    const float* Wq = (const float*)d_in[2];
    const float* bq = (const float*)d_in[3];
    const float* Wk = (const float*)d_in[4];
    const float* bk = (const float*)d_in[5];
    const float* Wv = (const float*)d_in[6];
    const float* bv = (const float*)d_in[7];
    float* out = (float*)d_out;

    float* out_attn = out;                       // (B,NH,N)
    float* out_k    = out_attn + SZ_ATTN;        // (B,NH,N,D)
    float* out_q    = out_k + SZ_HEADS;          // (B,NH,N,D)
    float* out_ctx  = out_q + SZ_HEADS;          // (B,NH,N,D)
    float* out_sc   = out_ctx + SZ_HEADS;        // (B,NH,N,N)

    int*   padd = (int*)d_ws;
    float* v_ws = (float*)((char*)d_ws + 256);   // (B,NH,N,D) 16 MB

    hipMemsetAsync(out_attn, 0, SZ_ATTN*sizeof(float), stream);
    padd_kernel<<<B_, 256, 0, stream>>>(pv, padd);

    dim3 pg(H_/128, (B_*N_)/128, 3);             // (8, 32, 3)
    proj3_mfma_kernel<<<pg, 256, 0, stream>>>(hs, Wq, bq, out_q,
                                              Wk, bk, out_k,
                                              Wv, bv, v_ws);

    dim3 fg(N_/128, B_*NH_);                     // (8, 64)
    fused_attn_kernel<<<fg, 256, 0, stream>>>(out_q, out_k, v_ws, padd,
                                              out_sc, out_ctx, out_attn);
}

// Round 5
// 536.243 us; speedup vs baseline: 1.9162x; 1.2441x over previous
//
#include <hip/hip_runtime.h>
#include <math.h>

#define B_ 4
#define N_ 1024
#define H_ 1024
#define NH_ 16
#define D_ 64

#define SZ_ATTN (B_*NH_*N_)
#define SZ_HEADS (B_*NH_*N_*D_)

typedef __attribute__((ext_vector_type(8))) short short8v;
typedef __attribute__((ext_vector_type(4))) short short4v;
typedef __attribute__((ext_vector_type(4))) float floatx4;

__device__ inline unsigned short f2bf(float x) {
    union { float f; unsigned int u; } v; v.f = x;
    unsigned int r = v.u + 0x7FFFu + ((v.u >> 16) & 1u);   // RNE
    return (unsigned short)(r >> 16);
}
__device__ inline float bf2f(unsigned short u) {
    union { unsigned int i; float f; } v; v.i = ((unsigned int)u) << 16;
    return v.f;
}

// ---------------------------------------------------------------------------
// padd[b] = index of first zero in padding_vector[b,:], or N
// ---------------------------------------------------------------------------
__global__ void padd_kernel(const int* __restrict__ pv, int* __restrict__ padd) {
    __shared__ int mn;
    const int b = blockIdx.x;
    if (threadIdx.x == 0) mn = N_;
    __syncthreads();
    for (int m = threadIdx.x; m < N_; m += blockDim.x)
        if (pv[b*N_ + m] == 0) atomicMin(&mn, m);
    __syncthreads();
    if (threadIdx.x == 0) padd[b] = mn;
}

// ---------------------------------------------------------------------------
// Q/K/V projections via bf16 MFMA (unchanged from round 4; ~126 us).
// ---------------------------------------------------------------------------
__global__ __launch_bounds__(256)
void proj3_mfma_kernel(const float* __restrict__ X,
                       const float* __restrict__ Wq, const float* __restrict__ bq_, float* __restrict__ Oq,
                       const float* __restrict__ Wk, const float* __restrict__ bk_, float* __restrict__ Ok,
                       const float* __restrict__ Wv, const float* __restrict__ bv_, float* __restrict__ Ov)
{
    const int which = blockIdx.z;
    const float* __restrict__ W    = (which == 0) ? Wq  : (which == 1) ? Wk  : Wv;
    const float* __restrict__ bias = (which == 0) ? bq_ : (which == 1) ? bk_ : bv_;
    float* __restrict__ outH       = (which == 0) ? Oq  : (which == 1) ? Ok  : Ov;

    __shared__ __align__(16) unsigned short Abf[128*64];
    __shared__ __align__(16) unsigned short Bbf[128*64];

    const int tid  = threadIdx.x;
    const int lane = tid & 63;
    const int w    = tid >> 6;
    const int wr   = w >> 1, wc = w & 1;
    const int fr   = lane & 15, hi = lane >> 4;
    const int i0 = blockIdx.y * 128;
    const int j0 = blockIdx.x * 128;

    floatx4 acc[4][4];
    #pragma unroll
    for (int mi = 0; mi < 4; ++mi)
        #pragma unroll
        for (int ni = 0; ni < 4; ++ni)
            acc[mi][ni] = (floatx4){0.f, 0.f, 0.f, 0.f};

    for (int kt = 0; kt < H_; kt += 64) {
        __syncthreads();
        #pragma unroll
        for (int l = 0; l < 4; ++l) {
            const int e = tid + 256*l;
            const int row = e >> 3, kc = e & 7;
            const int sw = ((kc ^ (row & 7)) << 3);
            {
                const float* src = X + (size_t)(i0+row)*H_ + kt + kc*8;
                const float4 xa = *(const float4*)(src);
                const float4 xb = *(const float4*)(src + 4);
                short8v pk;
                pk[0] = (short)f2bf(xa.x); pk[1] = (short)f2bf(xa.y);
                pk[2] = (short)f2bf(xa.z); pk[3] = (short)f2bf(xa.w);
                pk[4] = (short)f2bf(xb.x); pk[5] = (short)f2bf(xb.y);
                pk[6] = (short)f2bf(xb.z); pk[7] = (short)f2bf(xb.w);
                *(short8v*)&Abf[row*64 + sw] = pk;
            }
            {
                const float* src = W + (size_t)(j0+row)*H_ + kt + kc*8;
                const float4 wa = *(const float4*)(src);
                const float4 wb = *(const float4*)(src + 4);
                short8v pk;
                pk[0] = (short)f2bf(wa.x); pk[1] = (short)f2bf(wa.y);
                pk[2] = (short)f2bf(wa.z); pk[3] = (short)f2bf(wa.w);
                pk[4] = (short)f2bf(wb.x); pk[5] = (short)f2bf(wb.y);
                pk[6] = (short)f2bf(wb.z); pk[7] = (short)f2bf(wb.w);
                *(short8v*)&Bbf[row*64 + sw] = pk;
            }
        }
        __syncthreads();

        #pragma unroll
        for (int ks = 0; ks < 2; ++ks) {
            short8v a[4], b[4];
            #pragma unroll
            for (int mi = 0; mi < 4; ++mi) {
                const int row = wr*64 + mi*16 + fr;
                a[mi] = *(const short8v*)&Abf[row*64 + (((ks*4 + hi) ^ (fr & 7)) << 3)];
            }
            #pragma unroll
            for (int ni = 0; ni < 4; ++ni) {
                const int row = wc*64 + ni*16 + fr;
                b[ni] = *(const short8v*)&Bbf[row*64 + (((ks*4 + hi) ^ (fr & 7)) << 3)];
            }
            #pragma unroll
            for (int mi = 0; mi < 4; ++mi)
                #pragma unroll
                for (int ni = 0; ni < 4; ++ni)
                    acc[mi][ni] = __builtin_amdgcn_mfma_f32_16x16x32_bf16(
                        a[mi], b[ni], acc[mi][ni], 0, 0, 0);
        }
    }

    #pragma unroll
    for (int ni = 0; ni < 4; ++ni) {
        const int j = j0 + wc*64 + ni*16 + fr;
        const int head = j >> 6, d = j & 63;
        const float bvj = bias[j];
        #pragma unroll
        for (int mi = 0; mi < 4; ++mi) {
            #pragma unroll
            for (int reg = 0; reg < 4; ++reg) {
                const int i = i0 + wr*64 + mi*16 + hi*4 + reg;
                const int bb = i >> 10, n = i & 1023;
                outH[((size_t)(bb*NH_ + head)*N_ + n)*D_ + d] = acc[mi][ni][reg] + bvj;
            }
        }
    }
}

// ---------------------------------------------------------------------------
// Fused attention via bf16 MFMA. Per block: 128 query rows, 4 waves, each
// wave owns 32 rows (stats stay wave-local).
// Pass 1: m-steps of 64: stage K-tile bf16 swizzled; QK^T via MFMA;
//         scale, write raw fp32 S; online masked row max/sumexp (shfl over
//         the 16 fr-lanes that tile the 64 m-columns).
// Pass 2: m-steps of 64: re-read S strip, P = exp(S-mx)*inv as bf16 in LDS
//         (swizzled), V^T bf16 in LDS; colsums -> attn atomics; P@V via MFMA.
// ---------------------------------------------------------------------------
__global__ __launch_bounds__(256)
void fused_attn_mfma(const float* __restrict__ Q, const float* __restrict__ K,
                     const float* __restrict__ Vh, const int* __restrict__ padd,
                     float* __restrict__ S, float* __restrict__ ctx,
                     float* __restrict__ attn)
{
    __shared__ __align__(16) unsigned short Abf[128*64]; // pass1: Q  pass2: P
    __shared__ __align__(16) unsigned short Bbf[64*64];  // pass1: K  pass2: V^T
    __shared__ float smx[128], sinv[128];
    __shared__ float cred[256];

    const int tid  = threadIdx.x;
    const int lane = tid & 63;
    const int w    = tid >> 6;           // wave id: rows w*32..w*32+31
    const int fr   = lane & 15, hi = lane >> 4;
    const int bh = blockIdx.y;
    const int n0 = blockIdx.x * 128;
    const int b  = bh >> 4;
    const int pd = padd[b];
    const float* Qb = Q  + (size_t)bh*N_*D_;
    const float* Kb = K  + (size_t)bh*N_*D_;
    const float* Vb = Vh + (size_t)bh*N_*D_;
    float* Sb = S + (size_t)bh*N_*N_;

    // ---- stage Q tile bf16 [128 rows][64 k], 16B chunks XOR-swizzled by row&7
    #pragma unroll
    for (int l = 0; l < 4; ++l) {
        const int e = tid + 256*l;             // 0..1023
        const int row = e >> 3, kc = e & 7;
        const float* src = Qb + (size_t)(n0+row)*D_ + kc*8;
        const float4 xa = *(const float4*)(src);
        const float4 xb = *(const float4*)(src + 4);
        short8v pk;
        pk[0] = (short)f2bf(xa.x); pk[1] = (short)f2bf(xa.y);
        pk[2] = (short)f2bf(xa.z); pk[3] = (short)f2bf(xa.w);
        pk[4] = (short)f2bf(xb.x); pk[5] = (short)f2bf(xb.y);
        pk[6] = (short)f2bf(xb.z); pk[7] = (short)f2bf(xb.w);
        *(short8v*)&Abf[row*64 + ((kc ^ (row & 7)) << 3)] = pk;
    }
    __syncthreads();

    // hoist Q fragments (invariant across m-steps): a-rows w*32 + mi*16 + fr
    short8v qa[2][2];
    #pragma unroll
    for (int mi = 0; mi < 2; ++mi)
        #pragma unroll
        for (int ks = 0; ks < 2; ++ks) {
            const int arow = w*32 + mi*16 + fr;
            qa[mi][ks] = *(const short8v*)&Abf[arow*64 + (((ks*4 + hi) ^ (fr & 7)) << 3)];
        }

    float run_mx[2][4], run_sm[2][4];
    #pragma unroll
    for (int mi = 0; mi < 2; ++mi)
        #pragma unroll
        for (int reg = 0; reg < 4; ++reg) { run_mx[mi][reg] = -INFINITY; run_sm[mi][reg] = 0.f; }

    // ---------------- pass 1: scores + online stats ----------------
    for (int m0 = 0; m0 < N_; m0 += 64) {
        // stage K tile bf16 [64 m-rows][64 k], swizzled
        #pragma unroll
        for (int l = 0; l < 2; ++l) {
            const int e = tid + 256*l;         // 0..511
            const int row = e >> 3, kc = e & 7;
            const float* src = Kb + (size_t)(m0+row)*D_ + kc*8;
            const float4 xa = *(const float4*)(src);
            const float4 xb = *(const float4*)(src + 4);
            short8v pk;
            pk[0] = (short)f2bf(xa.x); pk[1] = (short)f2bf(xa.y);
            pk[2] = (short)f2bf(xa.z); pk[3] = (short)f2bf(xa.w);
            pk[4] = (short)f2bf(xb.x); pk[5] = (short)f2bf(xb.y);
            pk[6] = (short)f2bf(xb.z); pk[7] = (short)f2bf(xb.w);
            *(short8v*)&Bbf[row*64 + ((kc ^ (row & 7)) << 3)] = pk;
        }
        __syncthreads();

        floatx4 sacc[2][4];
        #pragma unroll
        for (int mi = 0; mi < 2; ++mi)
            #pragma unroll
            for (int ni = 0; ni < 4; ++ni)
                sacc[mi][ni] = (floatx4){0.f, 0.f, 0.f, 0.f};

        #pragma unroll
        for (int ks = 0; ks < 2; ++ks) {
            short8v kb[4];
            #pragma unroll
            for (int ni = 0; ni < 4; ++ni) {
                const int brow = ni*16 + fr;
                kb[ni] = *(const short8v*)&Bbf[brow*64 + (((ks*4 + hi) ^ (fr & 7)) << 3)];
            }
            #pragma unroll
            for (int mi = 0; mi < 2; ++mi)
                #pragma unroll
                for (int ni = 0; ni < 4; ++ni)
                    sacc[mi][ni] = __builtin_amdgcn_mfma_f32_16x16x32_bf16(
                        qa[mi][ks], kb[ni], sacc[mi][ni], 0, 0, 0);
        }

        // scale + write raw scores (all rows/cols, unmasked).
        // C/D layout: col(m) = fr, row(n) = hi*4 + reg.
        #pragma unroll
        for (int mi = 0; mi < 2; ++mi)
            #pragma unroll
            for (int ni = 0; ni < 4; ++ni) {
                sacc[mi][ni] *= 0.125f;
                const int m = m0 + ni*16 + fr;
                #pragma unroll
                for (int reg = 0; reg < 4; ++reg) {
                    const int n = n0 + w*32 + mi*16 + hi*4 + reg;
                    Sb[(size_t)n*N_ + m] = sacc[mi][ni][reg];
                }
            }

        // online masked max / sum-exp per row (reduce over the 16 fr-lanes)
        if (m0 < pd) {
            #pragma unroll
            for (int mi = 0; mi < 2; ++mi)
                #pragma unroll
                for (int reg = 0; reg < 4; ++reg) {
                    float tm = -INFINITY;
                    #pragma unroll
                    for (int ni = 0; ni < 4; ++ni)
                        if (m0 + ni*16 + fr < pd) tm = fmaxf(tm, sacc[mi][ni][reg]);
                    tm = fmaxf(tm, __shfl_xor(tm, 1, 64));
                    tm = fmaxf(tm, __shfl_xor(tm, 2, 64));
                    tm = fmaxf(tm, __shfl_xor(tm, 4, 64));
                    tm = fmaxf(tm, __shfl_xor(tm, 8, 64));
                    const float nm = fmaxf(run_mx[mi][reg], tm);
                    float s = 0.f;
                    #pragma unroll
                    for (int ni = 0; ni < 4; ++ni)
                        if (m0 + ni*16 + fr < pd) s += __expf(sacc[mi][ni][reg] - nm);
                    s += __shfl_xor(s, 1, 64);
                    s += __shfl_xor(s, 2, 64);
                    s += __shfl_xor(s, 4, 64);
                    s += __shfl_xor(s, 8, 64);
                    run_sm[mi][reg] = run_sm[mi][reg]*__expf(run_mx[mi][reg] - nm) + s;
                    run_mx[mi][reg] = nm;
                }
        }
        __syncthreads();   // protect Bbf before next staging
    }

    // fully-masked n-tile: S already written; ctx rows are zero
    if (n0 >= pd) {
        #pragma unroll
        for (int l = 0; l < 8; ++l) {
            const int e = tid + 256*l;
            const int row = e >> 4, c4 = e & 15;
            float4 z; z.x = z.y = z.z = z.w = 0.f;
            *(float4*)(ctx + ((size_t)bh*N_ + n0 + row)*D_ + c4*4) = z;
        }
        return;
    }

    // finalize per-row stats into LDS (each wave owns its 32 rows)
    if (fr == 0) {
        #pragma unroll
        for (int mi = 0; mi < 2; ++mi)
            #pragma unroll
            for (int reg = 0; reg < 4; ++reg) {
                const int row = w*32 + mi*16 + hi*4 + reg;
                const bool v = (n0 + row) < pd;
                smx[row]  = v ? run_mx[mi][reg] : 0.f;
                sinv[row] = v ? 1.f/run_sm[mi][reg] : 0.f;
            }
    }
    __syncthreads();

    // ---------------- pass 2: probs -> attn colsums + P@V ----------------
    floatx4 acc2[2][4];
    #pragma unroll
    for (int mi = 0; mi < 2; ++mi)
        #pragma unroll
        for (int ni = 0; ni < 4; ++ni)
            acc2[mi][ni] = (floatx4){0.f, 0.f, 0.f, 0.f};

    for (int m0 = 0; m0 < pd; m0 += 64) {
        // stage P tile bf16 [128 n][64 m], swizzled by n&7
        #pragma unroll
        for (int l = 0; l < 8; ++l) {
            const int e = tid + 256*l;         // 0..2047
            const int row = e >> 4, c4 = e & 15;
            const int n = n0 + row;
            const int m = m0 + c4*4;
            const float4 s4 = *(const float4*)(Sb + (size_t)n*N_ + m);
            const bool rv = n < pd;
            const float fmx = smx[row], fiv = sinv[row];
            short4v pk;
            pk[0] = (short)f2bf((rv && m+0 < pd) ? __expf(s4.x - fmx)*fiv : 0.f);
            pk[1] = (short)f2bf((rv && m+1 < pd) ? __expf(s4.y - fmx)*fiv : 0.f);
            pk[2] = (short)f2bf((rv && m+2 < pd) ? __expf(s4.z - fmx)*fiv : 0.f);
            pk[3] = (short)f2bf((rv && m+3 < pd) ? __expf(s4.w - fmx)*fiv : 0.f);
            const int elem = row*64 + (((c4 >> 1) ^ (row & 7)) << 3) + (c4 & 1)*4;
            *(short4v*)&Abf[elem] = pk;
        }
        // stage V^T bf16 [64 d][64 m], swizzled by d&7
        {
            const int d = tid & 63, mg = tid >> 6;
            #pragma unroll
            for (int jj = 0; jj < 2; ++jj) {
                short8v pk;
                #pragma unroll
                for (int j = 0; j < 8; ++j)
                    pk[j] = (short)f2bf(Vb[(size_t)(m0 + mg*16 + jj*8 + j)*D_ + d]);
                const int chunk = mg*2 + jj;
                *(short8v*)&Bbf[d*64 + ((chunk ^ (d & 7)) << 3)] = pk;
            }
        }
        __syncthreads();

        // column sums of this probs tile -> attention_values
        {
            const int ml = tid & 63, q = tid >> 6;
            float cs = 0.f;
            #pragma unroll
            for (int i = 0; i < 32; ++i) {
                const int row = q*32 + i;
                cs += bf2f(Abf[row*64 + (((ml >> 3) ^ (row & 7)) << 3) + (ml & 7)]);
            }
            cred[tid] = cs;
        }
        __syncthreads();
        if (tid < 64) {
            const float vtot = cred[tid] + cred[tid+64] + cred[tid+128] + cred[tid+192];
            atomicAdd(&attn[(size_t)bh*N_ + m0 + tid], vtot);
        }

        // P @ V via MFMA (accumulate across m-tiles)
        #pragma unroll
        for (int ks = 0; ks < 2; ++ks) {
            short8v a[2], vfr[4];
            #pragma unroll
            for (int mi = 0; mi < 2; ++mi) {
                const int arow = w*32 + mi*16 + fr;
                a[mi] = *(const short8v*)&Abf[arow*64 + (((ks*4 + hi) ^ (fr & 7)) << 3)];
            }
            #pragma unroll
            for (int ni = 0; ni < 4; ++ni) {
                const int bd = ni*16 + fr;
                vfr[ni] = *(const short8v*)&Bbf[bd*64 + (((ks*4 + hi) ^ (fr & 7)) << 3)];
            }
            #pragma unroll
            for (int mi = 0; mi < 2; ++mi)
                #pragma unroll
                for (int ni = 0; ni < 4; ++ni)
                    acc2[mi][ni] = __builtin_amdgcn_mfma_f32_16x16x32_bf16(
                        a[mi], vfr[ni], acc2[mi][ni], 0, 0, 0);
        }
        __syncthreads();   // protect LDS before next tile's staging
    }

    // ctx write: rows n >= pd have all-zero P rows -> acc2 = 0 (correct)
    #pragma unroll
    for (int mi = 0; mi < 2; ++mi)
        #pragma unroll
        for (int ni = 0; ni < 4; ++ni) {
            const int d = ni*16 + fr;
            #pragma unroll
            for (int reg = 0; reg < 4; ++reg) {
                const int n = n0 + w*32 + mi*16 + hi*4 + reg;
                ctx[((size_t)bh*N_ + n)*D_ + d] = acc2[mi][ni][reg];
            }
        }
}

// ---------------------------------------------------------------------------
extern "C" void kernel_launch(void* const* d_in, const int* in_sizes, int n_in,
                              void* d_out, int out_size, void* d_ws, size_t ws_size,
                              hipStream_t stream)
{
    const float* hs = (const float*)d_in[0];
    const int*   pv = (const int*)d_in[1];
    const float* Wq = (const float*)d_in[2];
    const float* bq = (const float*)d_in[3];
    const float* Wk = (const float*)d_in[4];
    const float* bk = (const float*)d_in[5];
    const float* Wv = (const float*)d_in[6];
    const float* bv = (const float*)d_in[7];
    float* out = (float*)d_out;

    float* out_attn = out;                       // (B,NH,N)
    float* out_k    = out_attn + SZ_ATTN;        // (B,NH,N,D)
    float* out_q    = out_k + SZ_HEADS;          // (B,NH,N,D)
    float* out_ctx  = out_q + SZ_HEADS;          // (B,NH,N,D)
    float* out_sc   = out_ctx + SZ_HEADS;        // (B,NH,N,N)

    int*   padd = (int*)d_ws;
    float* v_ws = (float*)((char*)d_ws + 256);   // (B,NH,N,D) 16 MB

    hipMemsetAsync(out_attn, 0, SZ_ATTN*sizeof(float), stream);
    padd_kernel<<<B_, 256, 0, stream>>>(pv, padd);

    dim3 pg(H_/128, (B_*N_)/128, 3);             // (8, 32, 3)
    proj3_mfma_kernel<<<pg, 256, 0, stream>>>(hs, Wq, bq, out_q,
                                              Wk, bk, out_k,
                                              Wv, bv, v_ws);

    dim3 fg(N_/128, B_*NH_);                     // (8, 64)
    fused_attn_mfma<<<fg, 256, 0, stream>>>(out_q, out_k, v_ws, padd,
                                            out_sc, out_ctx, out_attn);
}

// Round 7
// 492.402 us; speedup vs baseline: 2.0868x; 1.0890x over previous
//
#include <hip/hip_runtime.h>
#include <math.h>

#define B_ 4
#define N_ 1024
#define H_ 1024
#define NH_ 16
#define D_ 64

#define SZ_ATTN (B_*NH_*N_)
#define SZ_HEADS (B_*NH_*N_*D_)

// tiled bf16 scratch geometry: tiles of 128 rows x 64 k, 1024 chunks of 8 bf16
#define XT_CHUNKS (32*16*1024)     // 524288 chunks = 8 MB
#define WT_CHUNKS (8*16*1024)      // 131072 chunks = 2 MB per W

typedef __attribute__((ext_vector_type(8))) short short8v;
typedef __attribute__((ext_vector_type(4))) short short4v;
typedef __attribute__((ext_vector_type(4))) float floatx4;

typedef __attribute__((address_space(1))) const unsigned int gau32;
typedef __attribute__((address_space(3))) unsigned int lau32;

__device__ inline void gl16(const unsigned short* g, unsigned short* l) {
    __builtin_amdgcn_global_load_lds((gau32*)g, (lau32*)l, 16, 0, 0);
}

__device__ inline unsigned short f2bf(float x) {
    union { float f; unsigned int u; } v; v.f = x;
    unsigned int r = v.u + 0x7FFFu + ((v.u >> 16) & 1u);   // RNE
    return (unsigned short)(r >> 16);
}
__device__ inline float bf2f(unsigned short u) {
    union { unsigned int i; float f; } v; v.i = ((unsigned int)u) << 16;
    return v.f;
}

// ---------------------------------------------------------------------------
// padd[b] = index of first zero in padding_vector[b,:], or N
// ---------------------------------------------------------------------------
__global__ void padd_kernel(const int* __restrict__ pv, int* __restrict__ padd) {
    __shared__ int mn;
    const int b = blockIdx.x;
    if (threadIdx.x == 0) mn = N_;
    __syncthreads();
    for (int m = threadIdx.x; m < N_; m += blockDim.x)
        if (pv[b*N_ + m] == 0) atomicMin(&mn, m);
    __syncthreads();
    if (threadIdx.x == 0) padd[b] = mn;
}

// ---------------------------------------------------------------------------
// One-shot fp32 -> bf16 conversion into tile-blocked, XOR-pre-swizzled layout.
// Chunk c within a tile: row = c>>3, kcs = c&7 holds source cols kc = kcs^(row&7).
// Layout: [X tiles (it*16+kt)][Wq tiles][Wk tiles][Wv tiles], contiguous.
// ---------------------------------------------------------------------------
__global__ __launch_bounds__(256)
void convert_kernel(const float* __restrict__ X,  const float* __restrict__ Wq,
                    const float* __restrict__ Wk, const float* __restrict__ Wv,
                    unsigned short* __restrict__ scratch)
{
    const int g = blockIdx.x*256 + threadIdx.x;
    const float* src;
    if (g < XT_CHUNKS) {
        const int c = g & 1023, t = g >> 10;          // t = it*16 + kt
        const int it = t >> 4, kt = t & 15;
        const int row = c >> 3, kcs = c & 7, kc = kcs ^ (row & 7);
        src = X + (size_t)(it*128 + row)*H_ + kt*64 + kc*8;
    } else {
        const int gw = g - XT_CHUNKS;
        const int which = gw >> 17;                   // WT_CHUNKS = 2^17
        const int rem = gw & (WT_CHUNKS-1);
        const int c = rem & 1023, t = rem >> 10;      // t = jt*16 + kt
        const int jt = t >> 4, kt = t & 15;
        const int row = c >> 3, kcs = c & 7, kc = kcs ^ (row & 7);
        const float* W = (which == 0) ? Wq : (which == 1) ? Wk : Wv;
        src = W + (size_t)(jt*128 + row)*H_ + kt*64 + kc*8;
    }
    const float4 a = *(const float4*)src;
    const float4 b = *(const float4*)(src + 4);
    short8v pk;
    pk[0] = (short)f2bf(a.x); pk[1] = (short)f2bf(a.y);
    pk[2] = (short)f2bf(a.z); pk[3] = (short)f2bf(a.w);
    pk[4] = (short)f2bf(b.x); pk[5] = (short)f2bf(b.y);
    pk[6] = (short)f2bf(b.z); pk[7] = (short)f2bf(b.w);
    *(short8v*)(scratch + (size_t)g*8) = pk;
}

// ---------------------------------------------------------------------------
// Q/K/V projections via bf16 MFMA, staging pre-converted tiles with
// global_load_lds (width 16). 128x128 tile, BK=64, 4 waves (2x2), 4x4 frags.
// ---------------------------------------------------------------------------
__global__ __launch_bounds__(256)
void proj3_mfma_kernel(const unsigned short* __restrict__ Xt,
                       const unsigned short* __restrict__ Wt_all,
                       const float* __restrict__ bq_, const float* __restrict__ bk_,
                       const float* __restrict__ bv_,
                       float* __restrict__ Oq, float* __restrict__ Ok,
                       float* __restrict__ Ov)
{
    const int which = blockIdx.z;
    const unsigned short* __restrict__ Wt = Wt_all + (size_t)which*WT_CHUNKS*8;
    const float* __restrict__ bias = (which == 0) ? bq_ : (which == 1) ? bk_ : bv_;
    float* __restrict__ outH       = (which == 0) ? Oq  : (which == 1) ? Ok  : Ov;

    __shared__ __align__(16) unsigned short Abf[128*64];
    __shared__ __align__(16) unsigned short Bbf[128*64];

    const int tid  = threadIdx.x;
    const int lane = tid & 63;
    const int w    = tid >> 6;
    const int wr   = w >> 1, wc = w & 1;
    const int fr   = lane & 15, hi = lane >> 4;
    const int i0 = blockIdx.y * 128;
    const int j0 = blockIdx.x * 128;

    floatx4 acc[4][4];
    #pragma unroll
    for (int mi = 0; mi < 4; ++mi)
        #pragma unroll
        for (int ni = 0; ni < 4; ++ni)
            acc[mi][ni] = (floatx4){0.f, 0.f, 0.f, 0.f};

    for (int ktile = 0; ktile < 16; ++ktile) {
        __syncthreads();
        const unsigned short* xsrc = Xt + (size_t)(blockIdx.y*16 + ktile)*8192;
        const unsigned short* wsrc = Wt + (size_t)(blockIdx.x*16 + ktile)*8192;
        #pragma unroll
        for (int l = 0; l < 4; ++l) {
            const int ch = l*256 + tid;
            gl16(xsrc + (size_t)ch*8, Abf + (size_t)ch*8);
            gl16(wsrc + (size_t)ch*8, Bbf + (size_t)ch*8);
        }
        __syncthreads();

        #pragma unroll
        for (int ks = 0; ks < 2; ++ks) {
            short8v a[4], b[4];
            #pragma unroll
            for (int mi = 0; mi < 4; ++mi) {
                const int row = wr*64 + mi*16 + fr;
                a[mi] = *(const short8v*)&Abf[row*64 + (((ks*4 + hi) ^ (fr & 7)) << 3)];
            }
            #pragma unroll
            for (int ni = 0; ni < 4; ++ni) {
                const int row = wc*64 + ni*16 + fr;
                b[ni] = *(const short8v*)&Bbf[row*64 + (((ks*4 + hi) ^ (fr & 7)) << 3)];
            }
            #pragma unroll
            for (int mi = 0; mi < 4; ++mi)
                #pragma unroll
                for (int ni = 0; ni < 4; ++ni)
                    acc[mi][ni] = __builtin_amdgcn_mfma_f32_16x16x32_bf16(
                        a[mi], b[ni], acc[mi][ni], 0, 0, 0);
        }
    }

    #pragma unroll
    for (int ni = 0; ni < 4; ++ni) {
        const int j = j0 + wc*64 + ni*16 + fr;
        const int head = j >> 6, d = j & 63;
        const float bvj = bias[j];
        #pragma unroll
        for (int mi = 0; mi < 4; ++mi) {
            #pragma unroll
            for (int reg = 0; reg < 4; ++reg) {
                const int i = i0 + wr*64 + mi*16 + hi*4 + reg;
                const int bb = i >> 10, n = i & 1023;
                outH[((size_t)(bb*NH_ + head)*N_ + n)*D_ + d] = acc[mi][ni][reg] + bvj;
            }
        }
    }
}

// ---------------------------------------------------------------------------
// Fused attention via bf16 MFMA (unchanged from round 5; ~200 us).
// ---------------------------------------------------------------------------
__global__ __launch_bounds__(256)
void fused_attn_mfma(const float* __restrict__ Q, const float* __restrict__ K,
                     const float* __restrict__ Vh, const int* __restrict__ padd,
                     float* __restrict__ S, float* __restrict__ ctx,
                     float* __restrict__ attn)
{
    __shared__ __align__(16) unsigned short Abf[128*64]; // pass1: Q  pass2: P
    __shared__ __align__(16) unsigned short Bbf[64*64];  // pass1: K  pass2: V^T
    __shared__ float smx[128], sinv[128];
    __shared__ float cred[256];

    const int tid  = threadIdx.x;
    const int lane = tid & 63;
    const int w    = tid >> 6;
    const int fr   = lane & 15, hi = lane >> 4;
    const int bh = blockIdx.y;
    const int n0 = blockIdx.x * 128;
    const int b  = bh >> 4;
    const int pd = padd[b];
    const float* Qb = Q  + (size_t)bh*N_*D_;
    const float* Kb = K  + (size_t)bh*N_*D_;
    const float* Vb = Vh + (size_t)bh*N_*D_;
    float* Sb = S + (size_t)bh*N_*N_;

    #pragma unroll
    for (int l = 0; l < 4; ++l) {
        const int e = tid + 256*l;
        const int row = e >> 3, kc = e & 7;
        const float* src = Qb + (size_t)(n0+row)*D_ + kc*8;
        const float4 xa = *(const float4*)(src);
        const float4 xb = *(const float4*)(src + 4);
        short8v pk;
        pk[0] = (short)f2bf(xa.x); pk[1] = (short)f2bf(xa.y);
        pk[2] = (short)f2bf(xa.z); pk[3] = (short)f2bf(xa.w);
        pk[4] = (short)f2bf(xb.x); pk[5] = (short)f2bf(xb.y);
        pk[6] = (short)f2bf(xb.z); pk[7] = (short)f2bf(xb.w);
        *(short8v*)&Abf[row*64 + ((kc ^ (row & 7)) << 3)] = pk;
    }
    __syncthreads();

    short8v qa[2][2];
    #pragma unroll
    for (int mi = 0; mi < 2; ++mi)
        #pragma unroll
        for (int ks = 0; ks < 2; ++ks) {
            const int arow = w*32 + mi*16 + fr;
            qa[mi][ks] = *(const short8v*)&Abf[arow*64 + (((ks*4 + hi) ^ (fr & 7)) << 3)];
        }

    float run_mx[2][4], run_sm[2][4];
    #pragma unroll
    for (int mi = 0; mi < 2; ++mi)
        #pragma unroll
        for (int reg = 0; reg < 4; ++reg) { run_mx[mi][reg] = -INFINITY; run_sm[mi][reg] = 0.f; }

    for (int m0 = 0; m0 < N_; m0 += 64) {
        #pragma unroll
        for (int l = 0; l < 2; ++l) {
            const int e = tid + 256*l;
            const int row = e >> 3, kc = e & 7;
            const float* src = Kb + (size_t)(m0+row)*D_ + kc*8;
            const float4 xa = *(const float4*)(src);
            const float4 xb = *(const float4*)(src + 4);
            short8v pk;
            pk[0] = (short)f2bf(xa.x); pk[1] = (short)f2bf(xa.y);
            pk[2] = (short)f2bf(xa.z); pk[3] = (short)f2bf(xa.w);
            pk[4] = (short)f2bf(xb.x); pk[5] = (short)f2bf(xb.y);
            pk[6] = (short)f2bf(xb.z); pk[7] = (short)f2bf(xb.w);
            *(short8v*)&Bbf[row*64 + ((kc ^ (row & 7)) << 3)] = pk;
        }
        __syncthreads();

        floatx4 sacc[2][4];
        #pragma unroll
        for (int mi = 0; mi < 2; ++mi)
            #pragma unroll
            for (int ni = 0; ni < 4; ++ni)
                sacc[mi][ni] = (floatx4){0.f, 0.f, 0.f, 0.f};

        #pragma unroll
        for (int ks = 0; ks < 2; ++ks) {
            short8v kb[4];
            #pragma unroll
            for (int ni = 0; ni < 4; ++ni) {
                const int brow = ni*16 + fr;
                kb[ni] = *(const short8v*)&Bbf[brow*64 + (((ks*4 + hi) ^ (fr & 7)) << 3)];
            }
            #pragma unroll
            for (int mi = 0; mi < 2; ++mi)
                #pragma unroll
                for (int ni = 0; ni < 4; ++ni)
                    sacc[mi][ni] = __builtin_amdgcn_mfma_f32_16x16x32_bf16(
                        qa[mi][ks], kb[ni], sacc[mi][ni], 0, 0, 0);
        }

        #pragma unroll
        for (int mi = 0; mi < 2; ++mi)
            #pragma unroll
            for (int ni = 0; ni < 4; ++ni) {
                sacc[mi][ni] *= 0.125f;
                const int m = m0 + ni*16 + fr;
                #pragma unroll
                for (int reg = 0; reg < 4; ++reg) {
                    const int n = n0 + w*32 + mi*16 + hi*4 + reg;
                    Sb[(size_t)n*N_ + m] = sacc[mi][ni][reg];
                }
            }

        if (m0 < pd) {
            #pragma unroll
            for (int mi = 0; mi < 2; ++mi)
                #pragma unroll
                for (int reg = 0; reg < 4; ++reg) {
                    float tm = -INFINITY;
                    #pragma unroll
                    for (int ni = 0; ni < 4; ++ni)
                        if (m0 + ni*16 + fr < pd) tm = fmaxf(tm, sacc[mi][ni][reg]);
                    tm = fmaxf(tm, __shfl_xor(tm, 1, 64));
                    tm = fmaxf(tm, __shfl_xor(tm, 2, 64));
                    tm = fmaxf(tm, __shfl_xor(tm, 4, 64));
                    tm = fmaxf(tm, __shfl_xor(tm, 8, 64));
                    const float nm = fmaxf(run_mx[mi][reg], tm);
                    float s = 0.f;
                    #pragma unroll
                    for (int ni = 0; ni < 4; ++ni)
                        if (m0 + ni*16 + fr < pd) s += __expf(sacc[mi][ni][reg] - nm);
                    s += __shfl_xor(s, 1, 64);
                    s += __shfl_xor(s, 2, 64);
                    s += __shfl_xor(s, 4, 64);
                    s += __shfl_xor(s, 8, 64);
                    run_sm[mi][reg] = run_sm[mi][reg]*__expf(run_mx[mi][reg] - nm) + s;
                    run_mx[mi][reg] = nm;
                }
        }
        __syncthreads();
    }

    if (n0 >= pd) {
        #pragma unroll
        for (int l = 0; l < 8; ++l) {
            const int e = tid + 256*l;
            const int row = e >> 4, c4 = e & 15;
            float4 z; z.x = z.y = z.z = z.w = 0.f;
            *(float4*)(ctx + ((size_t)bh*N_ + n0 + row)*D_ + c4*4) = z;
        }
        return;
    }

    if (fr == 0) {
        #pragma unroll
        for (int mi = 0; mi < 2; ++mi)
            #pragma unroll
            for (int reg = 0; reg < 4; ++reg) {
                const int row = w*32 + mi*16 + hi*4 + reg;
                const bool v = (n0 + row) < pd;
                smx[row]  = v ? run_mx[mi][reg] : 0.f;
                sinv[row] = v ? 1.f/run_sm[mi][reg] : 0.f;
            }
    }
    __syncthreads();

    floatx4 acc2[2][4];
    #pragma unroll
    for (int mi = 0; mi < 2; ++mi)
        #pragma unroll
        for (int ni = 0; ni < 4; ++ni)
            acc2[mi][ni] = (floatx4){0.f, 0.f, 0.f, 0.f};

    for (int m0 = 0; m0 < pd; m0 += 64) {
        #pragma unroll
        for (int l = 0; l < 8; ++l) {
            const int e = tid + 256*l;
            const int row = e >> 4, c4 = e & 15;
            const int n = n0 + row;
            const int m = m0 + c4*4;
            const float4 s4 = *(const float4*)(Sb + (size_t)n*N_ + m);
            const bool rv = n < pd;
            const float fmx = smx[row], fiv = sinv[row];
            short4v pk;
            pk[0] = (short)f2bf((rv && m+0 < pd) ? __expf(s4.x - fmx)*fiv : 0.f);
            pk[1] = (short)f2bf((rv && m+1 < pd) ? __expf(s4.y - fmx)*fiv : 0.f);
            pk[2] = (short)f2bf((rv && m+2 < pd) ? __expf(s4.z - fmx)*fiv : 0.f);
            pk[3] = (short)f2bf((rv && m+3 < pd) ? __expf(s4.w - fmx)*fiv : 0.f);
            const int elem = row*64 + (((c4 >> 1) ^ (row & 7)) << 3) + (c4 & 1)*4;
            *(short4v*)&Abf[elem] = pk;
        }
        {
            const int d = tid & 63, mg = tid >> 6;
            #pragma unroll
            for (int jj = 0; jj < 2; ++jj) {
                short8v pk;
                #pragma unroll
                for (int j = 0; j < 8; ++j)
                    pk[j] = (short)f2bf(Vb[(size_t)(m0 + mg*16 + jj*8 + j)*D_ + d]);
                const int chunk = mg*2 + jj;
                *(short8v*)&Bbf[d*64 + ((chunk ^ (d & 7)) << 3)] = pk;
            }
        }
        __syncthreads();

        {
            const int ml = tid & 63, q = tid >> 6;
            float cs = 0.f;
            #pragma unroll
            for (int i = 0; i < 32; ++i) {
                const int row = q*32 + i;
                cs += bf2f(Abf[row*64 + (((ml >> 3) ^ (row & 7)) << 3) + (ml & 7)]);
            }
            cred[tid] = cs;
        }
        __syncthreads();
        if (tid < 64) {
            const float vtot = cred[tid] + cred[tid+64] + cred[tid+128] + cred[tid+192];
            atomicAdd(&attn[(size_t)bh*N_ + m0 + tid], vtot);
        }

        #pragma unroll
        for (int ks = 0; ks < 2; ++ks) {
            short8v a[2], vfr[4];
            #pragma unroll
            for (int mi = 0; mi < 2; ++mi) {
                const int arow = w*32 + mi*16 + fr;
                a[mi] = *(const short8v*)&Abf[arow*64 + (((ks*4 + hi) ^ (fr & 7)) << 3)];
            }
            #pragma unroll
            for (int ni = 0; ni < 4; ++ni) {
                const int bd = ni*16 + fr;
                vfr[ni] = *(const short8v*)&Bbf[bd*64 + (((ks*4 + hi) ^ (fr & 7)) << 3)];
            }
            #pragma unroll
            for (int mi = 0; mi < 2; ++mi)
                #pragma unroll
                for (int ni = 0; ni < 4; ++ni)
                    acc2[mi][ni] = __builtin_amdgcn_mfma_f32_16x16x32_bf16(
                        a[mi], vfr[ni], acc2[mi][ni], 0, 0, 0);
        }
        __syncthreads();
    }

    #pragma unroll
    for (int mi = 0; mi < 2; ++mi)
        #pragma unroll
        for (int ni = 0; ni < 4; ++ni) {
            const int d = ni*16 + fr;
            #pragma unroll
            for (int reg = 0; reg < 4; ++reg) {
                const int n = n0 + w*32 + mi*16 + hi*4 + reg;
                ctx[((size_t)bh*N_ + n)*D_ + d] = acc2[mi][ni][reg];
            }
        }
}

// ---------------------------------------------------------------------------
extern "C" void kernel_launch(void* const* d_in, const int* in_sizes, int n_in,
                              void* d_out, int out_size, void* d_ws, size_t ws_size,
                              hipStream_t stream)
{
    const float* hs = (const float*)d_in[0];
    const int*   pv = (const int*)d_in[1];
    const float* Wq = (const float*)d_in[2];
    const float* bq = (const float*)d_in[3];
    const float* Wk = (const float*)d_in[4];
    const float* bk = (const float*)d_in[5];
    const float* Wv = (const float*)d_in[6];
    const float* bv = (const float*)d_in[7];
    float* out = (float*)d_out;

    float* out_attn = out;                       // (B,NH,N)
    float* out_k    = out_attn + SZ_ATTN;        // (B,NH,N,D)
    float* out_q    = out_k + SZ_HEADS;          // (B,NH,N,D)
    float* out_ctx  = out_q + SZ_HEADS;          // (B,NH,N,D)
    float* out_sc   = out_ctx + SZ_HEADS;        // (B,NH,N,N)

    int*   padd = (int*)d_ws;
    float* v_ws = (float*)((char*)d_ws + 256);   // (B,NH,N,D) 16 MB

    // bf16 tile scratch lives in out_sc; fully overwritten by fused_attn's S.
    unsigned short* scratch = (unsigned short*)out_sc;
    const unsigned short* Xt = scratch;
    const unsigned short* Wt = scratch + (size_t)XT_CHUNKS*8;

    hipMemsetAsync(out_attn, 0, SZ_ATTN*sizeof(float), stream);
    padd_kernel<<<B_, 256, 0, stream>>>(pv, padd);

    convert_kernel<<<(XT_CHUNKS + 3*WT_CHUNKS)/256, 256, 0, stream>>>(
        hs, Wq, Wk, Wv, scratch);

    dim3 pg(H_/128, (B_*N_)/128, 3);             // (8, 32, 3)
    proj3_mfma_kernel<<<pg, 256, 0, stream>>>(Xt, Wt, bq, bk, bv,
                                              out_q, out_k, v_ws);

    dim3 fg(N_/128, B_*NH_);                     // (8, 64)
    fused_attn_mfma<<<fg, 256, 0, stream>>>(out_q, out_k, v_ws, padd,
                                            out_sc, out_ctx, out_attn);
}

// Round 8
// 470.693 us; speedup vs baseline: 2.1831x; 1.0461x over previous
//
#include <hip/hip_runtime.h>
#include <math.h>

#define B_ 4
#define N_ 1024
#define H_ 1024
#define NH_ 16
#define D_ 64

#define SZ_ATTN (B_*NH_*N_)
#define SZ_HEADS (B_*NH_*N_*D_)

// tiled bf16 scratch geometry: tiles of 128 rows x 64 k, 1024 chunks of 8 bf16
#define XT_CHUNKS (32*16*1024)     // 524288 chunks = 8 MB
#define WT_CHUNKS (8*16*1024)      // 131072 chunks = 2 MB per W

typedef __attribute__((ext_vector_type(8))) short short8v;
typedef __attribute__((ext_vector_type(4))) float floatx4;

typedef __attribute__((address_space(1))) const unsigned int gau32;
typedef __attribute__((address_space(3))) unsigned int lau32;

__device__ inline void gl16(const unsigned short* g, unsigned short* l) {
    __builtin_amdgcn_global_load_lds((gau32*)g, (lau32*)l, 16, 0, 0);
}

__device__ inline unsigned short f2bf(float x) {
    union { float f; unsigned int u; } v; v.f = x;
    unsigned int r = v.u + 0x7FFFu + ((v.u >> 16) & 1u);   // RNE
    return (unsigned short)(r >> 16);
}
__device__ inline float bf2f(unsigned short u) {
    union { unsigned int i; float f; } v; v.i = ((unsigned int)u) << 16;
    return v.f;
}

// ---------------------------------------------------------------------------
// padd[b] = index of first zero in padding_vector[b,:], or N
// ---------------------------------------------------------------------------
__global__ void padd_kernel(const int* __restrict__ pv, int* __restrict__ padd) {
    __shared__ int mn;
    const int b = blockIdx.x;
    if (threadIdx.x == 0) mn = N_;
    __syncthreads();
    for (int m = threadIdx.x; m < N_; m += blockDim.x)
        if (pv[b*N_ + m] == 0) atomicMin(&mn, m);
    __syncthreads();
    if (threadIdx.x == 0) padd[b] = mn;
}

// ---------------------------------------------------------------------------
// One-shot fp32 -> bf16 conversion into tile-blocked, XOR-pre-swizzled layout.
// ---------------------------------------------------------------------------
__global__ __launch_bounds__(256)
void convert_kernel(const float* __restrict__ X,  const float* __restrict__ Wq,
                    const float* __restrict__ Wk, const float* __restrict__ Wv,
                    unsigned short* __restrict__ scratch)
{
    const int g = blockIdx.x*256 + threadIdx.x;
    const float* src;
    if (g < XT_CHUNKS) {
        const int c = g & 1023, t = g >> 10;          // t = it*16 + kt
        const int it = t >> 4, kt = t & 15;
        const int row = c >> 3, kcs = c & 7, kc = kcs ^ (row & 7);
        src = X + (size_t)(it*128 + row)*H_ + kt*64 + kc*8;
    } else {
        const int gw = g - XT_CHUNKS;
        const int which = gw >> 17;                   // WT_CHUNKS = 2^17
        const int rem = gw & (WT_CHUNKS-1);
        const int c = rem & 1023, t = rem >> 10;      // t = jt*16 + kt
        const int jt = t >> 4, kt = t & 15;
        const int row = c >> 3, kcs = c & 7, kc = kcs ^ (row & 7);
        const float* W = (which == 0) ? Wq : (which == 1) ? Wk : Wv;
        src = W + (size_t)(jt*128 + row)*H_ + kt*64 + kc*8;
    }
    const float4 a = *(const float4*)src;
    const float4 b = *(const float4*)(src + 4);
    short8v pk;
    pk[0] = (short)f2bf(a.x); pk[1] = (short)f2bf(a.y);
    pk[2] = (short)f2bf(a.z); pk[3] = (short)f2bf(a.w);
    pk[4] = (short)f2bf(b.x); pk[5] = (short)f2bf(b.y);
    pk[6] = (short)f2bf(b.z); pk[7] = (short)f2bf(b.w);
    *(short8v*)(scratch + (size_t)g*8) = pk;
}

// ---------------------------------------------------------------------------
// Q/K/V projections via bf16 MFMA + global_load_lds staging (round 7, ~80us).
// ---------------------------------------------------------------------------
__global__ __launch_bounds__(256)
void proj3_mfma_kernel(const unsigned short* __restrict__ Xt,
                       const unsigned short* __restrict__ Wt_all,
                       const float* __restrict__ bq_, const float* __restrict__ bk_,
                       const float* __restrict__ bv_,
                       float* __restrict__ Oq, float* __restrict__ Ok,
                       float* __restrict__ Ov)
{
    const int which = blockIdx.z;
    const unsigned short* __restrict__ Wt = Wt_all + (size_t)which*WT_CHUNKS*8;
    const float* __restrict__ bias = (which == 0) ? bq_ : (which == 1) ? bk_ : bv_;
    float* __restrict__ outH       = (which == 0) ? Oq  : (which == 1) ? Ok  : Ov;

    __shared__ __align__(16) unsigned short Abf[128*64];
    __shared__ __align__(16) unsigned short Bbf[128*64];

    const int tid  = threadIdx.x;
    const int lane = tid & 63;
    const int w    = tid >> 6;
    const int wr   = w >> 1, wc = w & 1;
    const int fr   = lane & 15, hi = lane >> 4;
    const int i0 = blockIdx.y * 128;
    const int j0 = blockIdx.x * 128;

    floatx4 acc[4][4];
    #pragma unroll
    for (int mi = 0; mi < 4; ++mi)
        #pragma unroll
        for (int ni = 0; ni < 4; ++ni)
            acc[mi][ni] = (floatx4){0.f, 0.f, 0.f, 0.f};

    for (int ktile = 0; ktile < 16; ++ktile) {
        __syncthreads();
        const unsigned short* xsrc = Xt + (size_t)(blockIdx.y*16 + ktile)*8192;
        const unsigned short* wsrc = Wt + (size_t)(blockIdx.x*16 + ktile)*8192;
        #pragma unroll
        for (int l = 0; l < 4; ++l) {
            const int ch = l*256 + tid;
            gl16(xsrc + (size_t)ch*8, Abf + (size_t)ch*8);
            gl16(wsrc + (size_t)ch*8, Bbf + (size_t)ch*8);
        }
        __syncthreads();

        #pragma unroll
        for (int ks = 0; ks < 2; ++ks) {
            short8v a[4], b[4];
            #pragma unroll
            for (int mi = 0; mi < 4; ++mi) {
                const int row = wr*64 + mi*16 + fr;
                a[mi] = *(const short8v*)&Abf[row*64 + (((ks*4 + hi) ^ (fr & 7)) << 3)];
            }
            #pragma unroll
            for (int ni = 0; ni < 4; ++ni) {
                const int row = wc*64 + ni*16 + fr;
                b[ni] = *(const short8v*)&Bbf[row*64 + (((ks*4 + hi) ^ (fr & 7)) << 3)];
            }
            #pragma unroll
            for (int mi = 0; mi < 4; ++mi)
                #pragma unroll
                for (int ni = 0; ni < 4; ++ni)
                    acc[mi][ni] = __builtin_amdgcn_mfma_f32_16x16x32_bf16(
                        a[mi], b[ni], acc[mi][ni], 0, 0, 0);
        }
    }

    #pragma unroll
    for (int ni = 0; ni < 4; ++ni) {
        const int j = j0 + wc*64 + ni*16 + fr;
        const int head = j >> 6, d = j & 63;
        const float bvj = bias[j];
        #pragma unroll
        for (int mi = 0; mi < 4; ++mi) {
            #pragma unroll
            for (int reg = 0; reg < 4; ++reg) {
                const int i = i0 + wr*64 + mi*16 + hi*4 + reg;
                const int bb = i >> 10, n = i & 1023;
                outH[((size_t)(bb*NH_ + head)*N_ + n)*D_ + d] = acc[mi][ni][reg] + bvj;
            }
        }
    }
}

// ---------------------------------------------------------------------------
// Fused attention via bf16 MFMA, v2:
//  pass 1: QK^T -> S staged in LDS -> coalesced dwordx4 S write; online stats.
//  pass 2: QK^T RECOMPUTED from registers+K restage (no S re-read from HBM),
//          P built in regs -> wave-local swizzled LDS; colsums; PV MFMA.
// ---------------------------------------------------------------------------
__global__ __launch_bounds__(256)
void fused_attn_mfma(const float* __restrict__ Q, const float* __restrict__ K,
                     const float* __restrict__ Vh, const int* __restrict__ padd,
                     float* __restrict__ S, float* __restrict__ ctx,
                     float* __restrict__ attn)
{
    __shared__ __align__(16) unsigned short Qbf[128*64]; // pass1: Q staging; pass2: P
    __shared__ __align__(16) unsigned short Kbf[64*64];  // K tile (both passes)
    __shared__ __align__(16) unsigned short Vbf[64*64];  // V^T tile (pass 2)
    __shared__ float Sst[128*68];                        // pass1 S staging (fp32)
    __shared__ float smx[128], sinv[128];
    __shared__ float cred[256];

    const int tid  = threadIdx.x;
    const int lane = tid & 63;
    const int w    = tid >> 6;           // wave id: rows w*32..w*32+31
    const int fr   = lane & 15, hi = lane >> 4;
    const int bh = blockIdx.y;
    const int n0 = blockIdx.x * 128;
    const int b  = bh >> 4;
    const int pd = padd[b];
    const float* Qb = Q  + (size_t)bh*N_*D_;
    const float* Kb = K  + (size_t)bh*N_*D_;
    const float* Vb = Vh + (size_t)bh*N_*D_;
    float* Sb = S + (size_t)bh*N_*N_;

    // ---- stage Q tile bf16 [128][64], 16B chunks XOR-swizzled by row&7
    #pragma unroll
    for (int l = 0; l < 4; ++l) {
        const int e = tid + 256*l;
        const int row = e >> 3, kc = e & 7;
        const float* src = Qb + (size_t)(n0+row)*D_ + kc*8;
        const float4 xa = *(const float4*)(src);
        const float4 xb = *(const float4*)(src + 4);
        short8v pk;
        pk[0] = (short)f2bf(xa.x); pk[1] = (short)f2bf(xa.y);
        pk[2] = (short)f2bf(xa.z); pk[3] = (short)f2bf(xa.w);
        pk[4] = (short)f2bf(xb.x); pk[5] = (short)f2bf(xb.y);
        pk[6] = (short)f2bf(xb.z); pk[7] = (short)f2bf(xb.w);
        *(short8v*)&Qbf[row*64 + ((kc ^ (row & 7)) << 3)] = pk;
    }
    __syncthreads();

    // hoist Q fragments (used by BOTH passes)
    short8v qa[2][2];
    #pragma unroll
    for (int mi = 0; mi < 2; ++mi)
        #pragma unroll
        for (int ks = 0; ks < 2; ++ks) {
            const int arow = w*32 + mi*16 + fr;
            qa[mi][ks] = *(const short8v*)&Qbf[arow*64 + (((ks*4 + hi) ^ (fr & 7)) << 3)];
        }
    __syncthreads();   // Qbf free after this (reused as P in pass 2)

    float run_mx[2][4], run_sm[2][4];
    #pragma unroll
    for (int mi = 0; mi < 2; ++mi)
        #pragma unroll
        for (int reg = 0; reg < 4; ++reg) { run_mx[mi][reg] = -INFINITY; run_sm[mi][reg] = 0.f; }

    // ---------------- pass 1: scores + online stats ----------------
    for (int m0 = 0; m0 < N_; m0 += 64) {
        #pragma unroll
        for (int l = 0; l < 2; ++l) {
            const int e = tid + 256*l;
            const int row = e >> 3, kc = e & 7;
            const float* src = Kb + (size_t)(m0+row)*D_ + kc*8;
            const float4 xa = *(const float4*)(src);
            const float4 xb = *(const float4*)(src + 4);
            short8v pk;
            pk[0] = (short)f2bf(xa.x); pk[1] = (short)f2bf(xa.y);
            pk[2] = (short)f2bf(xa.z); pk[3] = (short)f2bf(xa.w);
            pk[4] = (short)f2bf(xb.x); pk[5] = (short)f2bf(xb.y);
            pk[6] = (short)f2bf(xb.z); pk[7] = (short)f2bf(xb.w);
            *(short8v*)&Kbf[row*64 + ((kc ^ (row & 7)) << 3)] = pk;
        }
        __syncthreads();

        floatx4 sacc[2][4];
        #pragma unroll
        for (int mi = 0; mi < 2; ++mi)
            #pragma unroll
            for (int ni = 0; ni < 4; ++ni)
                sacc[mi][ni] = (floatx4){0.f, 0.f, 0.f, 0.f};

        #pragma unroll
        for (int ks = 0; ks < 2; ++ks) {
            short8v kb[4];
            #pragma unroll
            for (int ni = 0; ni < 4; ++ni) {
                const int brow = ni*16 + fr;
                kb[ni] = *(const short8v*)&Kbf[brow*64 + (((ks*4 + hi) ^ (fr & 7)) << 3)];
            }
            #pragma unroll
            for (int mi = 0; mi < 2; ++mi)
                #pragma unroll
                for (int ni = 0; ni < 4; ++ni)
                    sacc[mi][ni] = __builtin_amdgcn_mfma_f32_16x16x32_bf16(
                        qa[mi][ks], kb[ni], sacc[mi][ni], 0, 0, 0);
        }

        // scale + stash into Sst (2-way-conflict writes, free)
        #pragma unroll
        for (int mi = 0; mi < 2; ++mi)
            #pragma unroll
            for (int ni = 0; ni < 4; ++ni) {
                sacc[mi][ni] *= 0.125f;
                const int m = ni*16 + fr;
                #pragma unroll
                for (int reg = 0; reg < 4; ++reg) {
                    const int row = w*32 + mi*16 + hi*4 + reg;
                    Sst[row*68 + m] = sacc[mi][ni][reg];
                }
            }

        // online masked max / sum-exp per row
        if (m0 < pd) {
            #pragma unroll
            for (int mi = 0; mi < 2; ++mi)
                #pragma unroll
                for (int reg = 0; reg < 4; ++reg) {
                    float tm = -INFINITY;
                    #pragma unroll
                    for (int ni = 0; ni < 4; ++ni)
                        if (m0 + ni*16 + fr < pd) tm = fmaxf(tm, sacc[mi][ni][reg]);
                    tm = fmaxf(tm, __shfl_xor(tm, 1, 64));
                    tm = fmaxf(tm, __shfl_xor(tm, 2, 64));
                    tm = fmaxf(tm, __shfl_xor(tm, 4, 64));
                    tm = fmaxf(tm, __shfl_xor(tm, 8, 64));
                    const float nm = fmaxf(run_mx[mi][reg], tm);
                    float s = 0.f;
                    #pragma unroll
                    for (int ni = 0; ni < 4; ++ni)
                        if (m0 + ni*16 + fr < pd) s += __expf(sacc[mi][ni][reg] - nm);
                    s += __shfl_xor(s, 1, 64);
                    s += __shfl_xor(s, 2, 64);
                    s += __shfl_xor(s, 4, 64);
                    s += __shfl_xor(s, 8, 64);
                    run_sm[mi][reg] = run_sm[mi][reg]*__expf(run_mx[mi][reg] - nm) + s;
                    run_mx[mi][reg] = nm;
                }
        }
        __syncthreads();

        // coalesced S write: 8 x dwordx4 per thread
        #pragma unroll
        for (int l = 0; l < 8; ++l) {
            const int e = tid + 256*l;
            const int row = e >> 4, c4 = e & 15;
            const float4 v = *(const float4*)&Sst[row*68 + c4*4];
            *(float4*)(Sb + (size_t)(n0+row)*N_ + m0 + c4*4) = v;
        }
    }

    // fully-masked n-tile: S written; ctx rows zero; no attn contributions
    if (n0 >= pd) {
        #pragma unroll
        for (int l = 0; l < 8; ++l) {
            const int e = tid + 256*l;
            const int row = e >> 4, c4 = e & 15;
            float4 z; z.x = z.y = z.z = z.w = 0.f;
            *(float4*)(ctx + ((size_t)bh*N_ + n0 + row)*D_ + c4*4) = z;
        }
        return;
    }

    // finalize per-row stats (each wave owns its 32 rows)
    if (fr == 0) {
        #pragma unroll
        for (int mi = 0; mi < 2; ++mi)
            #pragma unroll
            for (int reg = 0; reg < 4; ++reg) {
                const int row = w*32 + mi*16 + hi*4 + reg;
                const bool v = (n0 + row) < pd;
                smx[row]  = v ? run_mx[mi][reg] : 0.f;
                sinv[row] = v ? 1.f/run_sm[mi][reg] : 0.f;
            }
    }
    __syncthreads();

    // hoist this thread's row stats into registers (loop-invariant)
    float mxr[2][4], ivr[2][4];
    #pragma unroll
    for (int mi = 0; mi < 2; ++mi)
        #pragma unroll
        for (int reg = 0; reg < 4; ++reg) {
            const int row = w*32 + mi*16 + hi*4 + reg;
            mxr[mi][reg] = smx[row];
            ivr[mi][reg] = sinv[row];
        }

    // ---------------- pass 2: QK^T recompute -> P -> colsums + PV ----------
    floatx4 acc2[2][4];
    #pragma unroll
    for (int mi = 0; mi < 2; ++mi)
        #pragma unroll
        for (int ni = 0; ni < 4; ++ni)
            acc2[mi][ni] = (floatx4){0.f, 0.f, 0.f, 0.f};

    for (int m0 = 0; m0 < pd; m0 += 64) {
        // stage K tile bf16 (same as pass 1)
        #pragma unroll
        for (int l = 0; l < 2; ++l) {
            const int e = tid + 256*l;
            const int row = e >> 3, kc = e & 7;
            const float* src = Kb + (size_t)(m0+row)*D_ + kc*8;
            const float4 xa = *(const float4*)(src);
            const float4 xb = *(const float4*)(src + 4);
            short8v pk;
            pk[0] = (short)f2bf(xa.x); pk[1] = (short)f2bf(xa.y);
            pk[2] = (short)f2bf(xa.z); pk[3] = (short)f2bf(xa.w);
            pk[4] = (short)f2bf(xb.x); pk[5] = (short)f2bf(xb.y);
            pk[6] = (short)f2bf(xb.z); pk[7] = (short)f2bf(xb.w);
            *(short8v*)&Kbf[row*64 + ((kc ^ (row & 7)) << 3)] = pk;
        }
        // stage V^T bf16 [64 d][64 m], swizzled by d&7
        {
            const int d = tid & 63, mg = tid >> 6;
            #pragma unroll
            for (int jj = 0; jj < 2; ++jj) {
                short8v pk;
                #pragma unroll
                for (int j = 0; j < 8; ++j)
                    pk[j] = (short)f2bf(Vb[(size_t)(m0 + mg*16 + jj*8 + j)*D_ + d]);
                const int chunk = mg*2 + jj;
                *(short8v*)&Vbf[d*64 + ((chunk ^ (d & 7)) << 3)] = pk;
            }
        }
        __syncthreads();

        // QK^T recompute (bit-identical to pass 1)
        floatx4 sacc[2][4];
        #pragma unroll
        for (int mi = 0; mi < 2; ++mi)
            #pragma unroll
            for (int ni = 0; ni < 4; ++ni)
                sacc[mi][ni] = (floatx4){0.f, 0.f, 0.f, 0.f};

        #pragma unroll
        for (int ks = 0; ks < 2; ++ks) {
            short8v kb[4];
            #pragma unroll
            for (int ni = 0; ni < 4; ++ni) {
                const int brow = ni*16 + fr;
                kb[ni] = *(const short8v*)&Kbf[brow*64 + (((ks*4 + hi) ^ (fr & 7)) << 3)];
            }
            #pragma unroll
            for (int mi = 0; mi < 2; ++mi)
                #pragma unroll
                for (int ni = 0; ni < 4; ++ni)
                    sacc[mi][ni] = __builtin_amdgcn_mfma_f32_16x16x32_bf16(
                        qa[mi][ks], kb[ni], sacc[mi][ni], 0, 0, 0);
        }

        // P = exp(S - mx)*inv, bf16, wave-local store into Qbf (swizzled)
        #pragma unroll
        for (int mi = 0; mi < 2; ++mi)
            #pragma unroll
            for (int ni = 0; ni < 4; ++ni) {
                const int mloc = ni*16 + fr;
                const bool mok = (m0 + mloc) < pd;
                #pragma unroll
                for (int reg = 0; reg < 4; ++reg) {
                    const int row = w*32 + mi*16 + hi*4 + reg;
                    float p = __expf(sacc[mi][ni][reg]*0.125f - mxr[mi][reg]) * ivr[mi][reg];
                    if (!mok) p = 0.f;
                    Qbf[row*64 + (((mloc >> 3) ^ (row & 7)) << 3) + (mloc & 7)] = f2bf(p);
                }
            }
        __syncthreads();

        // PV MFMA
        #pragma unroll
        for (int ks = 0; ks < 2; ++ks) {
            short8v a[2], vfr[4];
            #pragma unroll
            for (int mi = 0; mi < 2; ++mi) {
                const int arow = w*32 + mi*16 + fr;
                a[mi] = *(const short8v*)&Qbf[arow*64 + (((ks*4 + hi) ^ (fr & 7)) << 3)];
            }
            #pragma unroll
            for (int ni = 0; ni < 4; ++ni) {
                const int bd = ni*16 + fr;
                vfr[ni] = *(const short8v*)&Vbf[bd*64 + (((ks*4 + hi) ^ (fr & 7)) << 3)];
            }
            #pragma unroll
            for (int mi = 0; mi < 2; ++mi)
                #pragma unroll
                for (int ni = 0; ni < 4; ++ni)
                    acc2[mi][ni] = __builtin_amdgcn_mfma_f32_16x16x32_bf16(
                        a[mi], vfr[ni], acc2[mi][ni], 0, 0, 0);
        }

        // column sums of P (wave-local rows) -> attn atomics
        {
            const int ml = tid & 63, q = tid >> 6;
            float cs = 0.f;
            #pragma unroll
            for (int i = 0; i < 32; ++i) {
                const int row = q*32 + i;
                cs += bf2f(Qbf[row*64 + (((ml >> 3) ^ (row & 7)) << 3) + (ml & 7)]);
            }
            cred[tid] = cs;
        }
        __syncthreads();
        if (tid < 64) {
            const float vtot = cred[tid] + cred[tid+64] + cred[tid+128] + cred[tid+192];
            atomicAdd(&attn[(size_t)bh*N_ + m0 + tid], vtot);
        }
    }

    #pragma unroll
    for (int mi = 0; mi < 2; ++mi)
        #pragma unroll
        for (int ni = 0; ni < 4; ++ni) {
            const int d = ni*16 + fr;
            #pragma unroll
            for (int reg = 0; reg < 4; ++reg) {
                const int n = n0 + w*32 + mi*16 + hi*4 + reg;
                ctx[((size_t)bh*N_ + n)*D_ + d] = acc2[mi][ni][reg];
            }
        }
}

// ---------------------------------------------------------------------------
extern "C" void kernel_launch(void* const* d_in, const int* in_sizes, int n_in,
                              void* d_out, int out_size, void* d_ws, size_t ws_size,
                              hipStream_t stream)
{
    const float* hs = (const float*)d_in[0];
    const int*   pv = (const int*)d_in[1];
    const float* Wq = (const float*)d_in[2];
    const float* bq = (const float*)d_in[3];
    const float* Wk = (const float*)d_in[4];
    const float* bk = (const float*)d_in[5];
    const float* Wv = (const float*)d_in[6];
    const float* bv = (const float*)d_in[7];
    float* out = (float*)d_out;

    float* out_attn = out;                       // (B,NH,N)
    float* out_k    = out_attn + SZ_ATTN;        // (B,NH,N,D)
    float* out_q    = out_k + SZ_HEADS;          // (B,NH,N,D)
    float* out_ctx  = out_q + SZ_HEADS;          // (B,NH,N,D)
    float* out_sc   = out_ctx + SZ_HEADS;        // (B,NH,N,N)

    int*   padd = (int*)d_ws;
    float* v_ws = (float*)((char*)d_ws + 256);   // (B,NH,N,D) 16 MB

    // bf16 tile scratch lives in out_sc; fully overwritten by fused_attn's S.
    unsigned short* scratch = (unsigned short*)out_sc;
    const unsigned short* Xt = scratch;
    const unsigned short* Wt = scratch + (size_t)XT_CHUNKS*8;

    hipMemsetAsync(out_attn, 0, SZ_ATTN*sizeof(float), stream);
    padd_kernel<<<B_, 256, 0, stream>>>(pv, padd);

    convert_kernel<<<(XT_CHUNKS + 3*WT_CHUNKS)/256, 256, 0, stream>>>(
        hs, Wq, Wk, Wv, scratch);

    dim3 pg(H_/128, (B_*N_)/128, 3);             // (8, 32, 3)
    proj3_mfma_kernel<<<pg, 256, 0, stream>>>(Xt, Wt, bq, bk, bv,
                                              out_q, out_k, v_ws);

    dim3 fg(N_/128, B_*NH_);                     // (8, 64)
    fused_attn_mfma<<<fg, 256, 0, stream>>>(out_q, out_k, v_ws, padd,
                                            out_sc, out_ctx, out_attn);
}